// Round 1
// baseline (15747.003 us; speedup 1.0000x reference)
//
#include <hip/hip_runtime.h>
#include <math.h>

#define NN 8000
#define KK 32
#define HH 256
#define NHEADS 8
#define DHD 32
#define DE 128
#define HF 512   // MULT*H

struct P {
  const float *nf, *ef, *ear, *ang;
  const float *ln1n_g, *ln1n_b, *ln1e_g, *ln1e_b;
  const float *W_ea, *b_ea, *W_nh, *b_nh, *W_eh, *b_eh;
  const float *W_gate, *b_gate, *W_cand, *b_cand;
  const float *ascal, *W_in, *b_in, *W_out, *b_out, *aw;
  const float *ln2n_g, *ln2n_b, *ln2e_g, *ln2e_b;
  const float *Wn1, *bn1, *Wn2, *bn2, *We1, *be1, *We2, *be2;
  const int *nbrl, *nbrc;
  const float *nh;      // ws: LN'ed node features [N,H]
  float *on, *oe;       // outputs
};

__device__ __forceinline__ float gelu_f(float x) {
  float x3 = x * x * x;
  return 0.5f * x * (1.0f + tanhf(0.7978845608028654f * (x + 0.044715f * x3)));
}

// acc[i][j] += sum_k A[(rg*8+i)*lda + k] * W[k*ldw + cg + 64*j]
template<int KD, int NW>
__device__ __forceinline__ void mm_acc(float acc[8][NW],
    const float* __restrict__ W, int ldw,
    const float* __restrict__ A, int lda, int tid)
{
  const int rg = tid >> 6;
  const int cg = tid & 63;
  const float* Ab = A + rg * 8 * lda;
  const float* Wb = W + cg;
  for (int k = 0; k < KD; k += 4) {
    float a[8][4];
    #pragma unroll
    for (int i = 0; i < 8; ++i)
      *(float4*)(a[i]) = *(const float4*)(Ab + i * lda + k);
    #pragma unroll
    for (int kk = 0; kk < 4; ++kk) {
      float w[NW];
      #pragma unroll
      for (int j = 0; j < NW; ++j) w[j] = Wb[(k + kk) * ldw + 64 * j];
      #pragma unroll
      for (int i = 0; i < 8; ++i) {
        #pragma unroll
        for (int j = 0; j < NW; ++j) acc[i][j] = fmaf(a[i][kk], w[j], acc[i][j]);
      }
    }
  }
}

template<int NW>
__device__ __forceinline__ void bias_init(float acc[8][NW], const float* __restrict__ bias, int tid) {
  int cg = tid & 63;
  #pragma unroll
  for (int j = 0; j < NW; ++j) {
    float b = bias[cg + 64 * j];
    #pragma unroll
    for (int i = 0; i < 8; ++i) acc[i][j] = b;
  }
}

__device__ __forceinline__ void store_gelu(float* dst, float acc[8][4], int tid) {
  int rg = tid >> 6, cg = tid & 63;
  #pragma unroll
  for (int i = 0; i < 8; ++i)
    #pragma unroll
    for (int j = 0; j < 4; ++j) dst[(rg * 8 + i) * HH + cg + 64 * j] = gelu_f(acc[i][j]);
}

__device__ __forceinline__ void store_plain(float* dst, float acc[8][4], int tid) {
  int rg = tid >> 6, cg = tid & 63;
  #pragma unroll
  for (int i = 0; i < 8; ++i)
    #pragma unroll
    for (int j = 0; j < 4; ++j) dst[(rg * 8 + i) * HH + cg + 64 * j] = acc[i][j];
}

__global__ void node_ln_kernel(const float* __restrict__ x, const float* __restrict__ g,
                               const float* __restrict__ b, float* __restrict__ y)
{
  int row = blockIdx.x * 4 + (threadIdx.x >> 6);
  int lane = threadIdx.x & 63;
  const float4* xr = (const float4*)(x + (size_t)row * HH);
  float4 v = xr[lane];
  float s = v.x + v.y + v.z + v.w;
  float ss = v.x * v.x + v.y * v.y + v.z * v.z + v.w * v.w;
  #pragma unroll
  for (int m = 1; m < 64; m <<= 1) { s += __shfl_xor(s, m); ss += __shfl_xor(ss, m); }
  float mean = s * (1.f / HH);
  float var = ss * (1.f / HH) - mean * mean;
  float rstd = rsqrtf(var + 1e-5f);
  float4 gg = ((const float4*)g)[lane];
  float4 bb = ((const float4*)b)[lane];
  float4 o;
  o.x = (v.x - mean) * rstd * gg.x + bb.x;
  o.y = (v.y - mean) * rstd * gg.y + bb.y;
  o.z = (v.z - mean) * rstd * gg.z + bb.z;
  o.w = (v.w - mean) * rstd * gg.w + bb.w;
  ((float4*)(y + (size_t)row * HH))[lane] = o;
}

__launch_bounds__(256, 1)
__global__ void mega_kernel(P p)
{
  extern __shared__ float sm[];
  float* B0 = sm;            // 32x256 f32
  float* B1 = sm + 8192;
  float* B2 = sm + 16384;
  float* B3 = sm + 24576;
  const int n = blockIdx.x;
  const int tid = threadIdx.x;
  const int cnt = p.nbrc[n];

  // ---------- Phase A: edge_attr = gelu(ear @ W_ea + b_ea) -> B0 ----------
  {
    const float4* src = (const float4*)(p.ear + (size_t)n * KK * DE);
    for (int idx = tid; idx < KK * DE / 4; idx += 256) ((float4*)B3)[idx] = src[idx];
    __syncthreads();
    float acc[8][4]; bias_init<4>(acc, p.b_ea, tid);
    mm_acc<DE, 4>(acc, p.W_ea, HH, B3, DE, tid);
    store_gelu(B0, acc, tid);
    __syncthreads();
  }
  // ---------- Phase B: node_hidden = gelu(nh[nbr] @ W_nh + b_nh) -> B1 ----------
  {
    int r = tid >> 3, pp = tid & 7;
    int idx = p.nbrl[n * KK + r];
    const float4* src = (const float4*)(p.nh + (size_t)idx * HH);
    float4* dst = (float4*)(B3 + r * HH);
    #pragma unroll
    for (int jj = 0; jj < 8; ++jj) dst[pp + 8 * jj] = src[pp + 8 * jj];
    __syncthreads();
    float acc[8][4]; bias_init<4>(acc, p.b_nh, tid);
    mm_acc<HH, 4>(acc, p.W_nh, HH, B3, HH, tid);
    store_gelu(B1, acc, tid);
    __syncthreads();
  }
  // ---------- Phase C: eh = LN(edge_features) -> B3 ; edge_hidden -> B2 ----------
  {
    int r = tid >> 3, pp = tid & 7;
    const float* xr = p.ef + ((size_t)n * KK + r) * HH;
    float xv[32]; float s = 0.f, ss = 0.f;
    #pragma unroll
    for (int m4 = 0; m4 < 8; ++m4) {
      float4 v = *(const float4*)(xr + pp * 32 + m4 * 4);
      ((float4*)xv)[m4] = v;
      s += v.x + v.y + v.z + v.w;
      ss += v.x * v.x + v.y * v.y + v.z * v.z + v.w * v.w;
    }
    #pragma unroll
    for (int m = 1; m < 8; m <<= 1) { s += __shfl_xor(s, m); ss += __shfl_xor(ss, m); }
    float mean = s * (1.f / HH);
    float var = ss * (1.f / HH) - mean * mean;
    float rstd = rsqrtf(var + 1e-5f);
    #pragma unroll
    for (int m4 = 0; m4 < 8; ++m4) {
      int c = pp * 32 + m4 * 4;
      float4 g = *(const float4*)(p.ln1e_g + c);
      float4 b = *(const float4*)(p.ln1e_b + c);
      float4 v = ((float4*)xv)[m4];
      float4 o;
      o.x = (v.x - mean) * rstd * g.x + b.x;
      o.y = (v.y - mean) * rstd * g.y + b.y;
      o.z = (v.z - mean) * rstd * g.z + b.z;
      o.w = (v.w - mean) * rstd * g.w + b.w;
      *(float4*)(B3 + r * HH + c) = o;
    }
    __syncthreads();
    float acc[8][4]; bias_init<4>(acc, p.b_eh, tid);
    mm_acc<HH, 4>(acc, p.W_eh, HH, B3, HH, tid);
    store_gelu(B2, acc, tid);
    __syncthreads();
  }
  // ---------- Phase D: gate/cand -> message -> B3 ----------
  {
    float ag[8][4]; bias_init<4>(ag, p.b_gate, tid);
    float ac[8][4]; bias_init<4>(ac, p.b_cand, tid);
    mm_acc<HH, 4>(ag, p.W_gate, HH, B0, HH, tid);
    mm_acc<HH, 4>(ag, p.W_gate + HH * HH, HH, B1, HH, tid);
    mm_acc<HH, 4>(ac, p.W_cand, HH, B0, HH, tid);
    mm_acc<HH, 4>(ac, p.W_cand + HH * HH, HH, B1, HH, tid);
    int rg = tid >> 6, cg = tid & 63;
    #pragma unroll
    for (int i = 0; i < 8; ++i) {
      #pragma unroll
      for (int j = 0; j < 4; ++j) {
        int r = rg * 8 + i, c = cg + 64 * j;
        float g = 1.f / (1.f + expf(-ag[i][j]));
        float cd = tanhf(ac[i][j]);
        B3[r * HH + c] = g * cd + (1.f - g) * B2[r * HH + c];
      }
    }
    __syncthreads();
  }
  // ---------- Phase E: qkv -> B0 (q), B1 (k), B2 (v) ----------
  {
    float acc[8][4];
    bias_init<4>(acc, p.b_in, tid);
    mm_acc<HH, 4>(acc, p.W_in, 3 * HH, B3, HH, tid);
    store_plain(B0, acc, tid);
    bias_init<4>(acc, p.b_in + HH, tid);
    mm_acc<HH, 4>(acc, p.W_in + HH, 3 * HH, B3, HH, tid);
    store_plain(B1, acc, tid);
    bias_init<4>(acc, p.b_in + 2 * HH, tid);
    mm_acc<HH, 4>(acc, p.W_in + 2 * HH, 3 * HH, B3, HH, tid);
    store_plain(B2, acc, tid);
    __syncthreads();
  }
  // ---------- Phase F: attention -> ctx -> B3 ----------
  {
    const int h = tid >> 5, qi = tid & 31;
    float qv[32];
    #pragma unroll
    for (int d4 = 0; d4 < 8; ++d4)
      ((float4*)qv)[d4] = *(const float4*)(B0 + qi * HH + h * DHD + d4 * 4);
    float sc[32];
    const float ascal = p.ascal[h];
    const float* arow = p.ang + (((size_t)n * NHEADS + h) * KK + qi) * KK;
    #pragma unroll
    for (int k4 = 0; k4 < 8; ++k4) ((float4*)sc)[k4] = *(const float4*)(arow + k4 * 4);
    #pragma unroll
    for (int k_ = 0; k_ < KK; ++k_) {
      float d = 0.f;
      #pragma unroll
      for (int d4 = 0; d4 < 8; ++d4) {
        float4 kv = *(const float4*)(B1 + k_ * HH + h * DHD + d4 * 4);
        float4 qq = ((float4*)qv)[d4];
        d += qq.x * kv.x + qq.y * kv.y + qq.z * kv.z + qq.w * kv.w;
      }
      sc[k_] = d * 0.17677669529663687f + sc[k_] * ascal + (k_ < cnt ? 0.f : -1e9f);
    }
    float mx = sc[0];
    #pragma unroll
    for (int k_ = 1; k_ < KK; ++k_) mx = fmaxf(mx, sc[k_]);
    float ssum = 0.f;
    #pragma unroll
    for (int k_ = 0; k_ < KK; ++k_) { sc[k_] = expf(sc[k_] - mx); ssum += sc[k_]; }
    float inv = 1.f / ssum;
    float cacc[32];
    #pragma unroll
    for (int d = 0; d < 32; ++d) cacc[d] = 0.f;
    #pragma unroll
    for (int k_ = 0; k_ < KK; ++k_) {
      float pr = sc[k_];
      #pragma unroll
      for (int d4 = 0; d4 < 8; ++d4) {
        float4 vv = *(const float4*)(B2 + k_ * HH + h * DHD + d4 * 4);
        cacc[d4 * 4 + 0] = fmaf(pr, vv.x, cacc[d4 * 4 + 0]);
        cacc[d4 * 4 + 1] = fmaf(pr, vv.y, cacc[d4 * 4 + 1]);
        cacc[d4 * 4 + 2] = fmaf(pr, vv.z, cacc[d4 * 4 + 2]);
        cacc[d4 * 4 + 3] = fmaf(pr, vv.w, cacc[d4 * 4 + 3]);
      }
    }
    #pragma unroll
    for (int d4 = 0; d4 < 8; ++d4) {
      float4 o;
      o.x = cacc[d4 * 4 + 0] * inv;
      o.y = cacc[d4 * 4 + 1] * inv;
      o.z = cacc[d4 * 4 + 2] * inv;
      o.w = cacc[d4 * 4 + 3] * inv;
      *(float4*)(B3 + qi * HH + h * DHD + d4 * 4) = o;
    }
    __syncthreads();
  }
  // ---------- Phase G: eo = ctx @ W_out + b_out -> B0 ----------
  {
    float acc[8][4]; bias_init<4>(acc, p.b_out, tid);
    mm_acc<HH, 4>(acc, p.W_out, HH, B3, HH, tid);
    store_plain(B0, acc, tid);
    __syncthreads();
  }
  // ---------- Phase H: alpha aggregation + node path ----------
  {
    int k_ = tid >> 3, h = tid & 7;
    float aa = 0.f;
    #pragma unroll
    for (int d4 = 0; d4 < 8; ++d4) {
      float4 e = *(const float4*)(B0 + k_ * HH + h * DHD + d4 * 4);
      float4 w = *(const float4*)(p.aw + h * DHD + d4 * 4);
      aa += e.x * w.x + e.y * w.y + e.z * w.z + e.w * w.w;
    }
    aa = aa > 0.f ? aa : 0.2f * aa;
    aa = (k_ < cnt) ? aa : -1e9f;
    B1[k_ * 8 + h] = aa;
    __syncthreads();
    if (tid < 8) {
      float mx = -1e30f;
      for (int k2 = 0; k2 < KK; ++k2) mx = fmaxf(mx, B1[k2 * 8 + tid]);
      float s2 = 0.f;
      for (int k2 = 0; k2 < KK; ++k2) s2 += expf(B1[k2 * 8 + tid] - mx);
      float inv2 = 1.f / s2;
      for (int k2 = 0; k2 < KK; ++k2) B1[k2 * 8 + tid] = expf(B1[k2 * 8 + tid] - mx) * inv2;
    }
    __syncthreads();
    int c = tid;
    float no = 0.f;
    #pragma unroll
    for (int k2 = 0; k2 < KK; ++k2) no = fmaf(B1[k2 * 8 + (c >> 5)], B0[k2 * HH + c], no);
    float nodef = no + p.nf[(size_t)n * HH + c];
    B1[256 + c] = nodef;
    // node LN2 (reduce across 256 threads via wave shuffles + B2 scratch)
    float s3 = nodef, ss3 = nodef * nodef;
    #pragma unroll
    for (int m = 1; m < 64; m <<= 1) { s3 += __shfl_xor(s3, m); ss3 += __shfl_xor(ss3, m); }
    if ((tid & 63) == 0) { B2[tid >> 6] = s3; B2[4 + (tid >> 6)] = ss3; }
    __syncthreads();
    s3 = B2[0] + B2[1] + B2[2] + B2[3];
    ss3 = B2[4] + B2[5] + B2[6] + B2[7];
    float mean = s3 * (1.f / HH), var = ss3 * (1.f / HH) - mean * mean;
    float rstd = rsqrtf(var + 1e-5f);
    float xln = (nodef - mean) * rstd * p.ln2n_g[c] + p.ln2n_b[c];
    B1[512 + c] = xln;
    __syncthreads();
    // node FFN1
    float a0 = p.bn1[tid], a1 = p.bn1[tid + 256];
    for (int k2 = 0; k2 < HH; ++k2) {
      float x = B1[512 + k2];
      a0 = fmaf(x, p.Wn1[k2 * HF + tid], a0);
      a1 = fmaf(x, p.Wn1[k2 * HF + tid + 256], a1);
    }
    B1[1024 + tid] = gelu_f(a0);
    B1[1024 + 256 + tid] = gelu_f(a1);
    __syncthreads();
    // node FFN2 + residual -> out
    float a2 = p.bn2[tid];
    for (int k2 = 0; k2 < HF; ++k2) a2 = fmaf(B1[1024 + k2], p.Wn2[k2 * HH + tid], a2);
    p.on[(size_t)n * HH + tid] = B1[256 + tid] + a2;
    __syncthreads();
  }
  // ---------- Phase I: edge residual + LN2e + edge FFN -> out ----------
  {
    int r = tid >> 3, pp = tid & 7;
    const float* efr = p.ef + ((size_t)n * KK + r) * HH;
    float xv[32]; float s = 0.f, ss = 0.f;
    #pragma unroll
    for (int m4 = 0; m4 < 8; ++m4) {
      int c = pp * 32 + m4 * 4;
      float4 e = *(const float4*)(efr + c);
      float4 o = *(float4*)(B0 + r * HH + c);
      float4 x;
      x.x = o.x + e.x; x.y = o.y + e.y; x.z = o.z + e.z; x.w = o.w + e.w;
      *(float4*)(B0 + r * HH + c) = x;
      ((float4*)xv)[m4] = x;
      s += x.x + x.y + x.z + x.w;
      ss += x.x * x.x + x.y * x.y + x.z * x.z + x.w * x.w;
    }
    #pragma unroll
    for (int m = 1; m < 8; m <<= 1) { s += __shfl_xor(s, m); ss += __shfl_xor(ss, m); }
    float mean = s * (1.f / HH);
    float var = ss * (1.f / HH) - mean * mean;
    float rstd = rsqrtf(var + 1e-5f);
    #pragma unroll
    for (int m4 = 0; m4 < 8; ++m4) {
      int c = pp * 32 + m4 * 4;
      float4 g = *(const float4*)(p.ln2e_g + c);
      float4 b = *(const float4*)(p.ln2e_b + c);
      float4 v = ((float4*)xv)[m4];
      float4 o;
      o.x = (v.x - mean) * rstd * g.x + b.x;
      o.y = (v.y - mean) * rstd * g.y + b.y;
      o.z = (v.z - mean) * rstd * g.z + b.z;
      o.w = (v.w - mean) * rstd * g.w + b.w;
      *(float4*)(B3 + r * HH + c) = o;
    }
    __syncthreads();
    // FFN1: hidden[32][512] f32 spans B1..B2 (64KB)
    float acc8[8][8]; bias_init<8>(acc8, p.be1, tid);
    mm_acc<HH, 8>(acc8, p.We1, HF, B3, HH, tid);
    {
      int rg = tid >> 6, cg = tid & 63;
      #pragma unroll
      for (int i = 0; i < 8; ++i)
        #pragma unroll
        for (int j = 0; j < 8; ++j)
          B1[(rg * 8 + i) * HF + cg + 64 * j] = gelu_f(acc8[i][j]);
    }
    __syncthreads();
    // FFN2 + residual -> out
    float acc[8][4]; bias_init<4>(acc, p.be2, tid);
    mm_acc<HF, 4>(acc, p.We2, HH, B1, HF, tid);
    {
      int rg = tid >> 6, cg = tid & 63;
      #pragma unroll
      for (int i = 0; i < 8; ++i)
        #pragma unroll
        for (int j = 0; j < 4; ++j) {
          int r2 = rg * 8 + i, c2 = cg + 64 * j;
          p.oe[((size_t)n * KK + r2) * HH + c2] = acc[i][j] + B0[r2 * HH + c2];
        }
    }
  }
}

extern "C" void kernel_launch(void* const* d_in, const int* in_sizes, int n_in,
                              void* d_out, int out_size, void* d_ws, size_t ws_size,
                              hipStream_t stream)
{
  P p;
  p.nf     = (const float*)d_in[0];
  p.ef     = (const float*)d_in[1];
  p.ear    = (const float*)d_in[2];
  p.ang    = (const float*)d_in[3];
  p.ln1n_g = (const float*)d_in[4];  p.ln1n_b = (const float*)d_in[5];
  p.ln1e_g = (const float*)d_in[6];  p.ln1e_b = (const float*)d_in[7];
  p.W_ea   = (const float*)d_in[8];  p.b_ea   = (const float*)d_in[9];
  p.W_nh   = (const float*)d_in[10]; p.b_nh   = (const float*)d_in[11];
  p.W_eh   = (const float*)d_in[12]; p.b_eh   = (const float*)d_in[13];
  p.W_gate = (const float*)d_in[14]; p.b_gate = (const float*)d_in[15];
  p.W_cand = (const float*)d_in[16]; p.b_cand = (const float*)d_in[17];
  p.ascal  = (const float*)d_in[18];
  p.W_in   = (const float*)d_in[19]; p.b_in   = (const float*)d_in[20];
  p.W_out  = (const float*)d_in[21]; p.b_out  = (const float*)d_in[22];
  p.aw     = (const float*)d_in[23];
  p.ln2n_g = (const float*)d_in[24]; p.ln2n_b = (const float*)d_in[25];
  p.ln2e_g = (const float*)d_in[26]; p.ln2e_b = (const float*)d_in[27];
  p.Wn1    = (const float*)d_in[28]; p.bn1    = (const float*)d_in[29];
  p.Wn2    = (const float*)d_in[30]; p.bn2    = (const float*)d_in[31];
  p.We1    = (const float*)d_in[32]; p.be1    = (const float*)d_in[33];
  p.We2    = (const float*)d_in[34]; p.be2    = (const float*)d_in[35];
  p.nbrl   = (const int*)d_in[36];
  p.nbrc   = (const int*)d_in[37];
  p.nh     = (const float*)d_ws;
  p.on     = (float*)d_out;
  p.oe     = (float*)d_out + (size_t)NN * HH;

  node_ln_kernel<<<NN / 4, 256, 0, stream>>>((const float*)d_in[0],
                                             (const float*)d_in[4],
                                             (const float*)d_in[5],
                                             (float*)d_ws);

  (void)hipFuncSetAttribute((const void*)mega_kernel,
                            hipFuncAttributeMaxDynamicSharedMemorySize, 131072);
  mega_kernel<<<NN, 256, 131072, stream>>>(p);
}

// Round 2
// 2684.995 us; speedup vs baseline: 5.8648x; 5.8648x over previous
//
#include <hip/hip_runtime.h>
#include <math.h>

#define NN 8000
#define KK 32
#define HH 256
#define NHEADS 8
#define DE 128
#define HF 512

typedef __attribute__((ext_vector_type(8))) short bs8;
typedef __attribute__((ext_vector_type(4))) short bs4;
typedef __attribute__((ext_vector_type(4))) float f4;

// ---- LDS layout (ushort elems) ----
#define ACT0_OFF 0
#define ACT1_OFF 16896
#define ACT2_OFF 33792
#define ACT3_OFF 50688
#define PB_OFF   67584   // 4 waves x 1024 ; also NSTG [16][264]
#define SA_OFF   71808   // 512 floats
#define SNF_OFF  72832   // 512 floats
#define LNP_OFF  73856   // 16 floats
#define LDS_ELEMS 73888
#define LDS_BYTES (LDS_ELEMS * 2)

struct P {
  const float *nf, *ef, *ear, *ang;
  const float *ln1e_g, *ln1e_b;
  const float *b_ea, *b_nh, *b_eh, *b_gate, *b_cand;
  const float *ascal, *b_in, *b_out, *aw;
  const float *ln2n_g, *ln2n_b, *ln2e_g, *ln2e_b;
  const float *bn1, *bn2, *be1, *be2;
  const int *nbrl, *nbrc;
  const unsigned short *nhb;   // ws: LN'ed node features bf16 [N][256]
  const unsigned short *wtEA, *wtNH, *wtEH, *wtG, *wtC, *wtIN, *wtOUT, *wtN1, *wtN2, *wtE1, *wtE2;
  float *on, *oe;
};

__device__ __forceinline__ unsigned short f2b(float f) {
  unsigned int u = __float_as_uint(f);
  unsigned int r = (u + 0x7fffu + ((u >> 16) & 1u)) >> 16;
  return (unsigned short)r;
}
__device__ __forceinline__ float b2f(unsigned short u) {
  return __uint_as_float(((unsigned int)u) << 16);
}
__device__ __forceinline__ float fast_tanh(float x) {
  x = fminf(fmaxf(x, -12.f), 12.f);
  float e = __expf(2.f * x);
  return (e - 1.f) / (e + 1.f);
}
__device__ __forceinline__ float gelu_f(float x) {
  return 0.5f * x * (1.f + fast_tanh(0.7978845608f * (x + 0.044715f * x * x * x)));
}
__device__ __forceinline__ float sigmoid_f(float x) {
  return 1.f / (1.f + __expf(-x));
}

// D = A @ Wt^T ; A bf16 in LDS row-major [row][k] (stride LDA elems),
// Wt bf16 in global [outcol][k] (stride KW). kb < KSPL reads A0, else A1.
template<int RT, int NCT, int KB, int KSPL, int LDA0, int LDA1, int KW>
__device__ __forceinline__ void gemm_bf16(f4 acc[RT][NCT],
    const unsigned short* __restrict__ wt,
    const unsigned short* __restrict__ A0,
    const unsigned short* __restrict__ A1,
    int cs, int rowbase, int l)
{
  const int lm = l & 15;
  const int lg = (l >> 4) << 3;
  #pragma unroll
  for (int kb = 0; kb < KB; ++kb) {
    bs8 bfr[NCT];
    #pragma unroll
    for (int ct = 0; ct < NCT; ++ct) {
      const int col = cs + ct * 16 + lm;
      bfr[ct] = *(const bs8*)(wt + (size_t)col * KW + kb * 32 + lg);
    }
    bs8 afr[RT];
    #pragma unroll
    for (int rt = 0; rt < RT; ++rt) {
      if (kb < KSPL)
        afr[rt] = *(const bs8*)(A0 + (rowbase + rt * 16 + lm) * LDA0 + kb * 32 + lg);
      else
        afr[rt] = *(const bs8*)(A1 + (rowbase + rt * 16 + lm) * LDA1 + (kb - KSPL) * 32 + lg);
    }
    #pragma unroll
    for (int rt = 0; rt < RT; ++rt)
      #pragma unroll
      for (int ct = 0; ct < NCT; ++ct)
        acc[rt][ct] = __builtin_amdgcn_mfma_f32_16x16x32_bf16(afr[rt], bfr[ct], acc[rt][ct], 0, 0, 0);
  }
}

template<int RT, int NCT>
__device__ __forceinline__ void zero_acc(f4 acc[RT][NCT]) {
  #pragma unroll
  for (int rt = 0; rt < RT; ++rt)
    #pragma unroll
    for (int ct = 0; ct < NCT; ++ct) {
      acc[rt][ct][0] = 0.f; acc[rt][ct][1] = 0.f; acc[rt][ct][2] = 0.f; acc[rt][ct][3] = 0.f;
    }
}

// store D tiles (+bias, optional gelu) as bf16 into LDS [row][col] stride LDD
template<int RT, int NCT, int ACTF, int LDD>
__device__ __forceinline__ void store_bf16(unsigned short* dst,
    f4 acc[RT][NCT], const float* __restrict__ bias, int cs, int rowbase, int l)
{
  const int lm = l & 15;
  const int lr = (l >> 4) << 2;
  #pragma unroll
  for (int ct = 0; ct < NCT; ++ct) {
    const int col = cs + ct * 16 + lm;
    const float bv = bias[col];
    #pragma unroll
    for (int rt = 0; rt < RT; ++rt) {
      #pragma unroll
      for (int r = 0; r < 4; ++r) {
        float v = acc[rt][ct][r] + bv;
        if (ACTF == 1) v = gelu_f(v);
        dst[(rowbase + rt * 16 + lr + r) * LDD + col] = f2b(v);
      }
    }
  }
}

// ---------- pre-kernels ----------
__global__ void node_ln_bf16(const float* __restrict__ x, const float* __restrict__ g,
                             const float* __restrict__ b, unsigned short* __restrict__ y)
{
  int row = blockIdx.x * 4 + (threadIdx.x >> 6);
  int lane = threadIdx.x & 63;
  float4 v = ((const float4*)(x + (size_t)row * HH))[lane];
  float s = v.x + v.y + v.z + v.w;
  float ss = v.x * v.x + v.y * v.y + v.z * v.z + v.w * v.w;
  #pragma unroll
  for (int m = 1; m < 64; m <<= 1) { s += __shfl_xor(s, m); ss += __shfl_xor(ss, m); }
  float mean = s * (1.f / HH);
  float var = ss * (1.f / HH) - mean * mean;
  float rstd = rsqrtf(var + 1e-5f);
  float4 gg = ((const float4*)g)[lane];
  float4 bb = ((const float4*)b)[lane];
  unsigned short o[4];
  o[0] = f2b((v.x - mean) * rstd * gg.x + bb.x);
  o[1] = f2b((v.y - mean) * rstd * gg.y + bb.y);
  o[2] = f2b((v.z - mean) * rstd * gg.z + bb.z);
  o[3] = f2b((v.w - mean) * rstd * gg.w + bb.w);
  *(bs4*)(y + (size_t)row * HH + lane * 4) = *(bs4*)o;
}

// src fp32 [K][C] -> dst bf16 [C][K]
__global__ void wt_transpose(const float* __restrict__ src, unsigned short* __restrict__ dst,
                             int K, int C)
{
  __shared__ float tile[32][33];
  int tx = threadIdx.x & 31, ty = threadIdx.x >> 5;
  int bk = blockIdx.x, bc = blockIdx.y;
  #pragma unroll
  for (int i = 0; i < 4; ++i)
    tile[ty + i * 8][tx] = src[(size_t)(bk * 32 + ty + i * 8) * C + bc * 32 + tx];
  __syncthreads();
  #pragma unroll
  for (int i = 0; i < 4; ++i)
    dst[(size_t)(bc * 32 + ty + i * 8) * K + bk * 32 + tx] = f2b(tile[tx][ty + i * 8]);
}

// ---------- mega kernel: 2 nodes per block ----------
__launch_bounds__(256, 1)
__global__ void mega_kernel(P p)
{
  extern __shared__ unsigned short smem[];
  unsigned short* ACT0 = smem + ACT0_OFF;
  unsigned short* ACT1 = smem + ACT1_OFF;
  unsigned short* ACT2 = smem + ACT2_OFF;
  unsigned short* ACT3 = smem + ACT3_OFF;
  unsigned short* PB   = smem + PB_OFF;
  float* SA  = (float*)(smem + SA_OFF);
  float* SNF = (float*)(smem + SNF_OFF);
  float* LNP = (float*)(smem + LNP_OFF);

  const int tid = threadIdx.x;
  const int l = tid & 63;
  const int w = tid >> 6;
  const int lm = l & 15;
  const int lg = (l >> 4) << 3;
  const int lr = (l >> 4) << 2;
  const int cs64 = w * 64;
  const size_t ebase = (size_t)blockIdx.x * 64;       // edge row base
  const int n0g = blockIdx.x * 2;                     // first node id
  const int cnt0 = p.nbrc[n0g], cnt1 = p.nbrc[n0g + 1];

  // ---- Phase A: stage ear bf16 [64][136] into ACT3 ----
  {
    int row = tid >> 2, q4 = tid & 3;
    const float* src = p.ear + (ebase + row) * DE + q4 * 32;
    unsigned short* d = ACT3 + row * 136 + q4 * 32;
    #pragma unroll
    for (int j = 0; j < 8; ++j) {
      float4 v = ((const float4*)src)[j];
      unsigned short o[4] = { f2b(v.x), f2b(v.y), f2b(v.z), f2b(v.w) };
      *(bs4*)(d + j * 4) = *(bs4*)o;
    }
  }
  __syncthreads();
  // edge_attr = gelu(ear @ W_ea + b) -> ACT0
  {
    f4 acc[4][4]; zero_acc<4,4>(acc);
    gemm_bf16<4,4,4,4,136,136,128>(acc, p.wtEA, ACT3, ACT3, cs64, 0, l);
    store_bf16<4,4,1,264>(ACT0, acc, p.b_ea, cs64, 0, l);
  }
  __syncthreads();
  // ---- Phase B: gather nh bf16 -> ACT3 [64][264] ----
  {
    int row = tid >> 2, q4 = tid & 3;
    int ni = row >> 5, kn = row & 31;
    int idx = p.nbrl[(n0g + ni) * KK + kn];
    const unsigned short* src = p.nhb + (size_t)idx * HH + q4 * 64;
    unsigned short* d = ACT3 + row * 264 + q4 * 64;
    #pragma unroll
    for (int j = 0; j < 8; ++j) *(bs8*)(d + j * 8) = *(const bs8*)(src + j * 8);
  }
  __syncthreads();
  // node_hidden -> ACT1
  {
    f4 acc[4][4]; zero_acc<4,4>(acc);
    gemm_bf16<4,4,8,8,264,264,256>(acc, p.wtNH, ACT3, ACT3, cs64, 0, l);
    store_bf16<4,4,1,264>(ACT1, acc, p.b_nh, cs64, 0, l);
  }
  __syncthreads();
  // ---- Phase C: LN1e(ef) -> ACT3 ----
  {
    int row = tid >> 2, q4 = tid & 3;
    const float* src = p.ef + (ebase + row) * HH + q4 * 64;
    float s = 0.f, ss = 0.f;
    #pragma unroll
    for (int j = 0; j < 16; ++j) {
      float4 v = ((const float4*)src)[j];
      s += v.x + v.y + v.z + v.w;
      ss += v.x * v.x + v.y * v.y + v.z * v.z + v.w * v.w;
    }
    s += __shfl_xor(s, 1); ss += __shfl_xor(ss, 1);
    s += __shfl_xor(s, 2); ss += __shfl_xor(ss, 2);
    float mean = s * (1.f / HH);
    float var = ss * (1.f / HH) - mean * mean;
    float rstd = rsqrtf(var + 1e-5f);
    unsigned short* d = ACT3 + row * 264 + q4 * 64;
    #pragma unroll
    for (int j = 0; j < 16; ++j) {
      float4 v = ((const float4*)src)[j];
      int c = q4 * 64 + j * 4;
      float4 g = *(const float4*)(p.ln1e_g + c);
      float4 b = *(const float4*)(p.ln1e_b + c);
      unsigned short o[4];
      o[0] = f2b((v.x - mean) * rstd * g.x + b.x);
      o[1] = f2b((v.y - mean) * rstd * g.y + b.y);
      o[2] = f2b((v.z - mean) * rstd * g.z + b.z);
      o[3] = f2b((v.w - mean) * rstd * g.w + b.w);
      *(bs4*)(d + j * 4) = *(bs4*)o;
    }
  }
  __syncthreads();
  // edge_hidden -> ACT2
  {
    f4 acc[4][4]; zero_acc<4,4>(acc);
    gemm_bf16<4,4,8,8,264,264,256>(acc, p.wtEH, ACT3, ACT3, cs64, 0, l);
    store_bf16<4,4,1,264>(ACT2, acc, p.b_eh, cs64, 0, l);
  }
  __syncthreads();
  // ---- Phase D: gate -> sig -> ACT3 ; cand -> message -> ACT3 ----
  {
    f4 acc[4][4]; zero_acc<4,4>(acc);
    gemm_bf16<4,4,16,8,264,264,512>(acc, p.wtG, ACT0, ACT1, cs64, 0, l);
    #pragma unroll
    for (int ct = 0; ct < 4; ++ct) {
      int col = cs64 + ct * 16 + lm;
      float bv = p.b_gate[col];
      #pragma unroll
      for (int rt = 0; rt < 4; ++rt)
        #pragma unroll
        for (int r = 0; r < 4; ++r)
          ACT3[(rt * 16 + lr + r) * 264 + col] = f2b(sigmoid_f(acc[rt][ct][r] + bv));
    }
    zero_acc<4,4>(acc);
    gemm_bf16<4,4,16,8,264,264,512>(acc, p.wtC, ACT0, ACT1, cs64, 0, l);
    asm volatile("s_waitcnt lgkmcnt(0)" ::: "memory");
    #pragma unroll
    for (int ct = 0; ct < 4; ++ct) {
      int col = cs64 + ct * 16 + lm;
      float bv = p.b_cand[col];
      #pragma unroll
      for (int rt = 0; rt < 4; ++rt)
        #pragma unroll
        for (int r = 0; r < 4; ++r) {
          int row = rt * 16 + lr + r;
          float g = b2f(ACT3[row * 264 + col]);
          float eh = b2f(ACT2[row * 264 + col]);
          float c = fast_tanh(acc[rt][ct][r] + bv);
          ACT3[row * 264 + col] = f2b(g * c + (1.f - g) * eh);
        }
    }
  }
  __syncthreads();
  // ---- Phase E: qkv ----
  {
    f4 acc[4][4];
    zero_acc<4,4>(acc);
    gemm_bf16<4,4,8,8,264,264,256>(acc, p.wtIN, ACT3, ACT3, cs64, 0, l);
    store_bf16<4,4,0,264>(ACT0, acc, p.b_in, cs64, 0, l);            // q
    zero_acc<4,4>(acc);
    gemm_bf16<4,4,8,8,264,264,256>(acc, p.wtIN + 256 * 256, ACT3, ACT3, cs64, 0, l);
    store_bf16<4,4,0,264>(ACT1, acc, p.b_in + 256, cs64, 0, l);      // k
    zero_acc<4,4>(acc);
    gemm_bf16<4,4,8,8,264,264,256>(acc, p.wtIN + 512 * 256, ACT3, ACT3, cs64, 0, l);
    // v stored transposed: Vt[ni][d(256)][k(32)]
    #pragma unroll
    for (int ct = 0; ct < 4; ++ct) {
      int col = cs64 + ct * 16 + lm;
      float bv = p.b_in[512 + col];
      #pragma unroll
      for (int rt = 0; rt < 4; ++rt)
        #pragma unroll
        for (int r = 0; r < 4; ++r) {
          int krow = rt * 16 + lr + r;
          int ni = krow >> 5, kl = krow & 31;
          ACT2[((ni * 256 + col) << 5) + kl] = f2b(acc[rt][ct][r] + bv);
        }
    }
  }
  __syncthreads();
  // ---- Phase F: attention (4 (ni,h) pairs per wave) ----
  {
    unsigned short* Pw = PB + w * 1024;
    #pragma unroll
    for (int pp = 0; pp < 4; ++pp) {
      const int pair = (w << 2) + pp;
      const int ni = pair >> 3, h = pair & 7;
      const int rowb = ni * 32, colb = h * 32;
      const int cn = ni ? cnt1 : cnt0;
      const float asc = p.ascal[h];
      bs8 qf[2], kf[2];
      #pragma unroll
      for (int qt = 0; qt < 2; ++qt)
        qf[qt] = *(const bs8*)(ACT0 + (rowb + qt * 16 + lm) * 264 + colb + lg);
      #pragma unroll
      for (int kt = 0; kt < 2; ++kt)
        kf[kt] = *(const bs8*)(ACT1 + (rowb + kt * 16 + lm) * 264 + colb + lg);
      f4 z; z[0] = 0.f; z[1] = 0.f; z[2] = 0.f; z[3] = 0.f;
      f4 sc[2][2];
      #pragma unroll
      for (int qt = 0; qt < 2; ++qt)
        #pragma unroll
        for (int kt = 0; kt < 2; ++kt)
          sc[qt][kt] = __builtin_amdgcn_mfma_f32_16x16x32_bf16(qf[qt], kf[kt], z, 0, 0, 0);
      float inv[2][4];
      #pragma unroll
      for (int qt = 0; qt < 2; ++qt) {
        float sv[2][4];
        #pragma unroll
        for (int kt = 0; kt < 2; ++kt)
          #pragma unroll
          for (int r = 0; r < 4; ++r) {
            int q = qt * 16 + lr + r;
            int kidx = kt * 16 + lm;
            float ang = p.ang[((((size_t)(n0g + ni)) * 8 + h) * 32 + q) * 32 + kidx];
            sv[kt][r] = sc[qt][kt][r] * 0.17677669529663687f + ang * asc + (kidx < cn ? 0.f : -1e9f);
          }
        #pragma unroll
        for (int r = 0; r < 4; ++r) {
          float m = fmaxf(sv[0][r], sv[1][r]);
          m = fmaxf(m, __shfl_xor(m, 1));
          m = fmaxf(m, __shfl_xor(m, 2));
          m = fmaxf(m, __shfl_xor(m, 4));
          m = fmaxf(m, __shfl_xor(m, 8));
          float e0 = __expf(sv[0][r] - m), e1 = __expf(sv[1][r] - m);
          float sum = e0 + e1;
          sum += __shfl_xor(sum, 1);
          sum += __shfl_xor(sum, 2);
          sum += __shfl_xor(sum, 4);
          sum += __shfl_xor(sum, 8);
          inv[qt][r] = 1.f / sum;
          int q = qt * 16 + lr + r;
          Pw[q * 32 + lm] = f2b(e0);
          Pw[q * 32 + 16 + lm] = f2b(e1);
        }
      }
      asm volatile("s_waitcnt lgkmcnt(0)" ::: "memory");
      bs8 pf[2], vf[2];
      #pragma unroll
      for (int qt = 0; qt < 2; ++qt)
        pf[qt] = *(const bs8*)(Pw + (qt * 16 + lm) * 32 + lg);
      #pragma unroll
      for (int dt = 0; dt < 2; ++dt)
        vf[dt] = *(const bs8*)(ACT2 + ((ni * 256 + colb + dt * 16 + lm) << 5) + lg);
      f4 cx[2][2];
      #pragma unroll
      for (int qt = 0; qt < 2; ++qt)
        #pragma unroll
        for (int dt = 0; dt < 2; ++dt)
          cx[qt][dt] = __builtin_amdgcn_mfma_f32_16x16x32_bf16(pf[qt], vf[dt], z, 0, 0, 0);
      #pragma unroll
      for (int qt = 0; qt < 2; ++qt)
        #pragma unroll
        for (int dt = 0; dt < 2; ++dt)
          #pragma unroll
          for (int r = 0; r < 4; ++r) {
            int row = rowb + qt * 16 + lr + r;
            int col = colb + dt * 16 + lm;
            ACT3[row * 264 + col] = f2b(cx[qt][dt][r] * inv[qt][r]);
          }
    }
  }
  __syncthreads();
  // ---- Phase G: eo = ctx @ W_out + b -> ACT0 ----
  {
    f4 acc[4][4]; zero_acc<4,4>(acc);
    gemm_bf16<4,4,8,8,264,264,256>(acc, p.wtOUT, ACT3, ACT3, cs64, 0, l);
    store_bf16<4,4,0,264>(ACT0, acc, p.b_out, cs64, 0, l);
  }
  __syncthreads();
  // ---- Phase H: alpha aggregation + node path ----
  {
    #pragma unroll
    for (int itb = 0; itb < 2; ++itb) {
      int it = tid + itb * 256;
      int ni = it >> 8, rem = it & 255, k = rem >> 3, h = rem & 7;
      float aa = 0.f;
      #pragma unroll
      for (int j = 0; j < 8; ++j) {
        bs4 ev = *(const bs4*)(ACT0 + (ni * 32 + k) * 264 + h * 32 + j * 4);
        float4 av = *(const float4*)(p.aw + h * 32 + j * 4);
        aa += b2f((unsigned short)ev[0]) * av.x + b2f((unsigned short)ev[1]) * av.y
            + b2f((unsigned short)ev[2]) * av.z + b2f((unsigned short)ev[3]) * av.w;
      }
      aa = aa > 0.f ? aa : 0.2f * aa;
      aa = (k < (ni ? cnt1 : cnt0)) ? aa : -1e9f;
      SA[it] = aa;
    }
  }
  __syncthreads();
  if (tid < 16) {
    int ni = tid >> 3, h = tid & 7;
    float mx = -1e30f;
    for (int k = 0; k < 32; ++k) mx = fmaxf(mx, SA[ni * 256 + k * 8 + h]);
    float s = 0.f;
    for (int k = 0; k < 32; ++k) s += __expf(SA[ni * 256 + k * 8 + h] - mx);
    float inv = 1.f / s;
    for (int k = 0; k < 32; ++k) {
      float* a = &SA[ni * 256 + k * 8 + h];
      *a = __expf(*a - mx) * inv;
    }
  }
  __syncthreads();
  float nodef[2];
  {
    #pragma unroll
    for (int ni = 0; ni < 2; ++ni) {
      int c = tid, h = c >> 5;
      float no = 0.f;
      for (int k = 0; k < 32; ++k)
        no = fmaf(SA[ni * 256 + k * 8 + h], b2f(ACT0[(ni * 32 + k) * 264 + c]), no);
      nodef[ni] = no + p.nf[(size_t)(n0g + ni) * HH + c];
    }
    float s0 = nodef[0], ss0 = nodef[0] * nodef[0];
    float s1 = nodef[1], ss1 = nodef[1] * nodef[1];
    #pragma unroll
    for (int m = 1; m < 64; m <<= 1) {
      s0 += __shfl_xor(s0, m); ss0 += __shfl_xor(ss0, m);
      s1 += __shfl_xor(s1, m); ss1 += __shfl_xor(ss1, m);
    }
    if (l == 0) { LNP[w * 4] = s0; LNP[w * 4 + 1] = ss0; LNP[w * 4 + 2] = s1; LNP[w * 4 + 3] = ss1; }
  }
  __syncthreads();
  {
    unsigned short* NSTG = PB;  // [16][264]
    float S0 = LNP[0] + LNP[4] + LNP[8] + LNP[12];
    float SS0 = LNP[1] + LNP[5] + LNP[9] + LNP[13];
    float S1 = LNP[2] + LNP[6] + LNP[10] + LNP[14];
    float SS1 = LNP[3] + LNP[7] + LNP[11] + LNP[15];
    float mean0 = S0 * (1.f / HH), var0 = SS0 * (1.f / HH) - mean0 * mean0;
    float mean1 = S1 * (1.f / HH), var1 = SS1 * (1.f / HH) - mean1 * mean1;
    float rs0 = rsqrtf(var0 + 1e-5f), rs1 = rsqrtf(var1 + 1e-5f);
    float g = p.ln2n_g[tid], b = p.ln2n_b[tid];
    NSTG[tid] = f2b((nodef[0] - mean0) * rs0 * g + b);
    NSTG[264 + tid] = f2b((nodef[1] - mean1) * rs1 * g + b);
    SNF[tid] = nodef[0];
    SNF[256 + tid] = nodef[1];
  }
  __syncthreads();
  {
    unsigned short* NSTG = PB;
    unsigned short* NH1 = ACT1;  // [16][520]
    f4 acc[1][8]; zero_acc<1,8>(acc);
    gemm_bf16<1,8,8,8,264,264,256>(acc, p.wtN1, NSTG, NSTG, w * 128, 0, l);
    store_bf16<1,8,1,520>(NH1, acc, p.bn1, w * 128, 0, l);
  }
  __syncthreads();
  {
    unsigned short* NH1 = ACT1;
    f4 acc[1][4]; zero_acc<1,4>(acc);
    gemm_bf16<1,4,16,16,520,520,512>(acc, p.wtN2, NH1, NH1, cs64, 0, l);
    if (l < 16) {
      #pragma unroll
      for (int ct = 0; ct < 4; ++ct) {
        int col = cs64 + ct * 16 + lm;
        #pragma unroll
        for (int r = 0; r < 2; ++r)
          p.on[(size_t)(n0g + r) * HH + col] = acc[0][ct][r] + p.bn2[col] + SNF[r * 256 + col];
      }
    }
  }
  // ---- Phase I: edge residual + LN2e + edge FFN ----
  {
    int row = tid >> 2, q4 = tid & 3;
    const float* efs = p.ef + (ebase + row) * HH + q4 * 64;
    unsigned short* eor = ACT0 + row * 264 + q4 * 64;
    float s = 0.f, ss = 0.f;
    #pragma unroll
    for (int j = 0; j < 16; ++j) {
      float4 e = ((const float4*)efs)[j];
      float x0 = e.x + b2f(eor[j * 4]);
      float x1 = e.y + b2f(eor[j * 4 + 1]);
      float x2 = e.z + b2f(eor[j * 4 + 2]);
      float x3 = e.w + b2f(eor[j * 4 + 3]);
      unsigned short o[4] = { f2b(x0), f2b(x1), f2b(x2), f2b(x3) };
      *(bs4*)(eor + j * 4) = *(bs4*)o;
      s += x0 + x1 + x2 + x3;
      ss += x0 * x0 + x1 * x1 + x2 * x2 + x3 * x3;
    }
    s += __shfl_xor(s, 1); ss += __shfl_xor(ss, 1);
    s += __shfl_xor(s, 2); ss += __shfl_xor(ss, 2);
    float mean = s * (1.f / HH);
    float var = ss * (1.f / HH) - mean * mean;
    float rstd = rsqrtf(var + 1e-5f);
    asm volatile("s_waitcnt lgkmcnt(0)" ::: "memory");
    unsigned short* d = ACT3 + row * 264 + q4 * 64;
    #pragma unroll
    for (int j = 0; j < 16; ++j) {
      int c = q4 * 64 + j * 4;
      float4 g = *(const float4*)(p.ln2e_g + c);
      float4 b = *(const float4*)(p.ln2e_b + c);
      unsigned short o[4];
      o[0] = f2b((b2f(eor[j * 4]) - mean) * rstd * g.x + b.x);
      o[1] = f2b((b2f(eor[j * 4 + 1]) - mean) * rstd * g.y + b.y);
      o[2] = f2b((b2f(eor[j * 4 + 2]) - mean) * rstd * g.z + b.z);
      o[3] = f2b((b2f(eor[j * 4 + 3]) - mean) * rstd * g.w + b.w);
      *(bs4*)(d + j * 4) = *(bs4*)o;
    }
  }
  __syncthreads();
  {
    unsigned short* HID = ACT1;  // [64][520] spans ACT1+ACT2
    #pragma unroll
    for (int pass = 0; pass < 2; ++pass) {
      f4 acc[4][4]; zero_acc<4,4>(acc);
      gemm_bf16<4,4,8,8,264,264,256>(acc, p.wtE1, ACT3, ACT3, pass * 256 + cs64, 0, l);
      store_bf16<4,4,1,520>(HID, acc, p.be1, pass * 256 + cs64, 0, l);
    }
  }
  __syncthreads();
  {
    unsigned short* HID = ACT1;
    f4 acc[4][4]; zero_acc<4,4>(acc);
    gemm_bf16<4,4,16,16,520,520,512>(acc, p.wtE2, HID, HID, cs64, 0, l);
    #pragma unroll
    for (int ct = 0; ct < 4; ++ct) {
      int col = cs64 + ct * 16 + lm;
      float bv = p.be2[col];
      #pragma unroll
      for (int rt = 0; rt < 4; ++rt)
        #pragma unroll
        for (int r = 0; r < 4; ++r) {
          int row = rt * 16 + lr + r;
          p.oe[(ebase + row) * HH + col] = acc[rt][ct][r] + bv + b2f(ACT0[row * 264 + col]);
        }
    }
  }
}

extern "C" void kernel_launch(void* const* d_in, const int* in_sizes, int n_in,
                              void* d_out, int out_size, void* d_ws, size_t ws_size,
                              hipStream_t stream)
{
  P p;
  p.nf     = (const float*)d_in[0];
  p.ef     = (const float*)d_in[1];
  p.ear    = (const float*)d_in[2];
  p.ang    = (const float*)d_in[3];
  const float* ln1n_g = (const float*)d_in[4];
  const float* ln1n_b = (const float*)d_in[5];
  p.ln1e_g = (const float*)d_in[6];  p.ln1e_b = (const float*)d_in[7];
  const float* W_ea   = (const float*)d_in[8];  p.b_ea   = (const float*)d_in[9];
  const float* W_nh   = (const float*)d_in[10]; p.b_nh   = (const float*)d_in[11];
  const float* W_eh   = (const float*)d_in[12]; p.b_eh   = (const float*)d_in[13];
  const float* W_gate = (const float*)d_in[14]; p.b_gate = (const float*)d_in[15];
  const float* W_cand = (const float*)d_in[16]; p.b_cand = (const float*)d_in[17];
  p.ascal  = (const float*)d_in[18];
  const float* W_in   = (const float*)d_in[19]; p.b_in   = (const float*)d_in[20];
  const float* W_out  = (const float*)d_in[21]; p.b_out  = (const float*)d_in[22];
  p.aw     = (const float*)d_in[23];
  p.ln2n_g = (const float*)d_in[24]; p.ln2n_b = (const float*)d_in[25];
  p.ln2e_g = (const float*)d_in[26]; p.ln2e_b = (const float*)d_in[27];
  const float* Wn1 = (const float*)d_in[28]; p.bn1 = (const float*)d_in[29];
  const float* Wn2 = (const float*)d_in[30]; p.bn2 = (const float*)d_in[31];
  const float* We1 = (const float*)d_in[32]; p.be1 = (const float*)d_in[33];
  const float* We2 = (const float*)d_in[34]; p.be2 = (const float*)d_in[35];
  p.nbrl   = (const int*)d_in[36];
  p.nbrc   = (const int*)d_in[37];
  p.on     = (float*)d_out;
  p.oe     = (float*)d_out + (size_t)NN * HH;

  // ws layout: nh bf16 table, then transposed bf16 weights
  size_t off = 0;
  auto alloc = [&](size_t elems) {
    unsigned short* q = (unsigned short*)((char*)d_ws + off);
    off += elems * 2;
    return q;
  };
  unsigned short* nhb = alloc((size_t)NN * HH);
  unsigned short* wtEA  = alloc(256 * 128);
  unsigned short* wtNH  = alloc(256 * 256);
  unsigned short* wtEH  = alloc(256 * 256);
  unsigned short* wtG   = alloc(256 * 512);
  unsigned short* wtC   = alloc(256 * 512);
  unsigned short* wtIN  = alloc(768 * 256);
  unsigned short* wtOUT = alloc(256 * 256);
  unsigned short* wtN1  = alloc(512 * 256);
  unsigned short* wtN2  = alloc(256 * 512);
  unsigned short* wtE1  = alloc(512 * 256);
  unsigned short* wtE2  = alloc(256 * 512);
  p.nhb = nhb;
  p.wtEA = wtEA; p.wtNH = wtNH; p.wtEH = wtEH; p.wtG = wtG; p.wtC = wtC;
  p.wtIN = wtIN; p.wtOUT = wtOUT; p.wtN1 = wtN1; p.wtN2 = wtN2; p.wtE1 = wtE1; p.wtE2 = wtE2;

  node_ln_bf16<<<NN / 4, 256, 0, stream>>>((const float*)d_in[0], ln1n_g, ln1n_b, nhb);

  auto tr = [&](const float* src, unsigned short* dst, int K, int C) {
    wt_transpose<<<dim3(K / 32, C / 32), 256, 0, stream>>>(src, dst, K, C);
  };
  tr(W_ea, wtEA, 128, 256);
  tr(W_nh, wtNH, 256, 256);
  tr(W_eh, wtEH, 256, 256);
  tr(W_gate, wtG, 512, 256);
  tr(W_cand, wtC, 512, 256);
  tr(W_in, wtIN, 256, 768);
  tr(W_out, wtOUT, 256, 256);
  tr(Wn1, wtN1, 256, 512);
  tr(Wn2, wtN2, 512, 256);
  tr(We1, wtE1, 256, 512);
  tr(We2, wtE2, 512, 256);

  (void)hipFuncSetAttribute((const void*)mega_kernel,
                            hipFuncAttributeMaxDynamicSharedMemorySize, LDS_BYTES);
  mega_kernel<<<NN / 2, 256, LDS_BYTES, stream>>>(p);
}

// Round 3
// 2537.724 us; speedup vs baseline: 6.2052x; 1.0580x over previous
//
#include <hip/hip_runtime.h>
#include <math.h>

#define NN 8000
#define KK 32
#define HH 256
#define DE 128

typedef __attribute__((ext_vector_type(8))) short bs8;
typedef __attribute__((ext_vector_type(4))) short bs4;
typedef __attribute__((ext_vector_type(4))) float f4;

// ---- LDS layout (ushort elem offsets) ----
#define ACT0_OFF 0        // [32][264]
#define ACT3_OFF 8448     // [32][264]
#define ACT1_OFF 16896    // [32][264]  (edge-FFN hidden [32][520] spans ACT1+VTB)
#define VTB_OFF  25344    // [32][264] ehid  /  Vt [256][40]
#define RR_OFF   35584    // 5248 elems: Pt 4x[32][40] (phase F) / H-phase scratch
#define LDS_ELEMS 40832
#define LDS_BYTES (LDS_ELEMS * 2)
// RR sub-offsets (elems), used in phase H (Pt is dead by then)
#define SA_U   0
#define SNF_U  512
#define LNP_U  1024
#define NSTG_U 1088
#define NH1_U  1360

struct P {
  const float *nf, *ef, *ear, *ang;
  const float *ln1e_g, *ln1e_b;
  const float *b_ea, *b_nh, *b_eh, *b_gate, *b_cand;
  const float *ascal, *b_in, *b_out, *aw;
  const float *ln2n_g, *ln2n_b, *ln2e_g, *ln2e_b;
  const float *bn1, *bn2, *be1, *be2;
  const int *nbrl, *nbrc;
  const unsigned short *nhb;
  const unsigned short *wtEA, *wtNH, *wtEH, *wtG, *wtC, *wtIN, *wtOUT, *wtN1, *wtN2, *wtE1, *wtE2;
  float *on, *oe;
};

__device__ __forceinline__ unsigned short f2b(float f) {
  unsigned int u = __float_as_uint(f);
  unsigned int r = (u + 0x7fffu + ((u >> 16) & 1u)) >> 16;
  return (unsigned short)r;
}
__device__ __forceinline__ float b2f(unsigned short u) {
  return __uint_as_float(((unsigned int)u) << 16);
}
__device__ __forceinline__ float fast_tanh(float x) {
  x = fminf(fmaxf(x, -12.f), 12.f);
  float e = __expf(2.f * x);
  return (e - 1.f) / (e + 1.f);
}
__device__ __forceinline__ float gelu_f(float x) {
  return 0.5f * x * (1.f + fast_tanh(0.7978845608f * (x + 0.044715f * x * x * x)));
}
__device__ __forceinline__ float sigmoid_f(float x) {
  return 1.f / (1.f + __expf(-x));
}

// D^T convention: acc[rt][ct] = mfma(W_frag, act_frag). Lane (l) holds
// act_row = rt*16 + (l&15), outcols = cs + ct*16 + (l>>4)*4 + r  (4 consecutive).
template<int RT, int NCT, int KB, int KSPL, int LDA0, int LDA1, int KW>
__device__ __forceinline__ void gemm_T(f4 acc[RT][NCT],
    const unsigned short* __restrict__ wt,
    const unsigned short* __restrict__ A0,
    const unsigned short* __restrict__ A1,
    int cs, int l)
{
  const int lm = l & 15;
  const int lg = (l >> 4) << 3;
  #pragma unroll
  for (int kb = 0; kb < KB; ++kb) {
    bs8 wfr[NCT];
    #pragma unroll
    for (int ct = 0; ct < NCT; ++ct)
      wfr[ct] = *(const bs8*)(wt + (size_t)(cs + ct * 16 + lm) * KW + kb * 32 + lg);
    bs8 afr[RT];
    #pragma unroll
    for (int rt = 0; rt < RT; ++rt) {
      if (kb < KSPL)
        afr[rt] = *(const bs8*)(A0 + (rt * 16 + lm) * LDA0 + kb * 32 + lg);
      else
        afr[rt] = *(const bs8*)(A1 + (rt * 16 + lm) * LDA1 + (kb - KSPL) * 32 + lg);
    }
    #pragma unroll
    for (int rt = 0; rt < RT; ++rt)
      #pragma unroll
      for (int ct = 0; ct < NCT; ++ct)
        acc[rt][ct] = __builtin_amdgcn_mfma_f32_16x16x32_bf16(wfr[ct], afr[rt], acc[rt][ct], 0, 0, 0);
  }
}

template<int RT, int NCT>
__device__ __forceinline__ void zero_acc(f4 acc[RT][NCT]) {
  #pragma unroll
  for (int rt = 0; rt < RT; ++rt)
    #pragma unroll
    for (int ct = 0; ct < NCT; ++ct) {
      acc[rt][ct][0] = 0.f; acc[rt][ct][1] = 0.f; acc[rt][ct][2] = 0.f; acc[rt][ct][3] = 0.f;
    }
}

// vectorized store: 4 consecutive cols per lane -> ds_write_b64
template<int RT, int NCT, int ACTF, int LDD>
__device__ __forceinline__ void store_T(unsigned short* dst,
    f4 acc[RT][NCT], const float* __restrict__ bias, int cs, int l)
{
  const int lm = l & 15;
  const int lr = (l >> 4) << 2;
  #pragma unroll
  for (int ct = 0; ct < NCT; ++ct) {
    f4 bv = *(const f4*)(bias + cs + ct * 16 + lr);
    #pragma unroll
    for (int rt = 0; rt < RT; ++rt) {
      unsigned short o[4];
      #pragma unroll
      for (int r = 0; r < 4; ++r) {
        float v = acc[rt][ct][r] + bv[r];
        if (ACTF == 1) v = gelu_f(v);
        o[r] = f2b(v);
      }
      *(bs4*)(dst + (rt * 16 + lm) * LDD + cs + ct * 16 + lr) = *(bs4*)o;
    }
  }
}

// ---------- pre-kernels ----------
__global__ void node_ln_bf16(const float* __restrict__ x, const float* __restrict__ g,
                             const float* __restrict__ b, unsigned short* __restrict__ y)
{
  int row = blockIdx.x * 4 + (threadIdx.x >> 6);
  int lane = threadIdx.x & 63;
  float4 v = ((const float4*)(x + (size_t)row * HH))[lane];
  float s = v.x + v.y + v.z + v.w;
  float ss = v.x * v.x + v.y * v.y + v.z * v.z + v.w * v.w;
  #pragma unroll
  for (int m = 1; m < 64; m <<= 1) { s += __shfl_xor(s, m); ss += __shfl_xor(ss, m); }
  float mean = s * (1.f / HH);
  float var = ss * (1.f / HH) - mean * mean;
  float rstd = rsqrtf(var + 1e-5f);
  float4 gg = ((const float4*)g)[lane];
  float4 bb = ((const float4*)b)[lane];
  unsigned short o[4];
  o[0] = f2b((v.x - mean) * rstd * gg.x + bb.x);
  o[1] = f2b((v.y - mean) * rstd * gg.y + bb.y);
  o[2] = f2b((v.z - mean) * rstd * gg.z + bb.z);
  o[3] = f2b((v.w - mean) * rstd * gg.w + bb.w);
  *(bs4*)(y + (size_t)row * HH + lane * 4) = *(bs4*)o;
}

__global__ void wt_transpose(const float* __restrict__ src, unsigned short* __restrict__ dst,
                             int K, int C)
{
  __shared__ float tile[32][33];
  int tx = threadIdx.x & 31, ty = threadIdx.x >> 5;
  int bk = blockIdx.x, bc = blockIdx.y;
  #pragma unroll
  for (int i = 0; i < 4; ++i)
    tile[ty + i * 8][tx] = src[(size_t)(bk * 32 + ty + i * 8) * C + bc * 32 + tx];
  __syncthreads();
  #pragma unroll
  for (int i = 0; i < 4; ++i)
    dst[(size_t)(bc * 32 + ty + i * 8) * K + bk * 32 + tx] = f2b(tile[tx][ty + i * 8]);
}

// ---------- mega kernel: 1 node per block, 2 blocks/CU ----------
__launch_bounds__(256, 2)
__global__ void mega_kernel(P p)
{
  extern __shared__ unsigned short smem[];
  unsigned short* ACT0 = smem + ACT0_OFF;
  unsigned short* ACT3 = smem + ACT3_OFF;
  unsigned short* ACT1 = smem + ACT1_OFF;
  unsigned short* VTB  = smem + VTB_OFF;
  unsigned short* RRu  = smem + RR_OFF;

  const int tid = threadIdx.x;
  const int l = tid & 63;
  const int w = tid >> 6;
  const int lm = l & 15;
  const int lg = (l >> 4) << 3;
  const int lr = (l >> 4) << 2;
  const int cs64 = w * 64;
  const int n = blockIdx.x;
  const size_t ebase = (size_t)n * KK;
  const int cnt = p.nbrc[n];

  // ---- Phase 1: stage ear bf16 [32][136] -> ACT3 ; edge_attr -> ACT0 ----
  {
    int row = tid >> 3, q = tid & 7;
    const float* src = p.ear + (ebase + row) * DE + q * 16;
    unsigned short* d = ACT3 + row * 136 + q * 16;
    #pragma unroll
    for (int j = 0; j < 4; ++j) {
      float4 v = ((const float4*)src)[j];
      unsigned short o[4] = { f2b(v.x), f2b(v.y), f2b(v.z), f2b(v.w) };
      *(bs4*)(d + j * 4) = *(bs4*)o;
    }
  }
  __syncthreads();
  {
    f4 acc[2][4]; zero_acc<2,4>(acc);
    gemm_T<2,4,4,4,136,136,128>(acc, p.wtEA, ACT3, ACT3, cs64, l);
    store_T<2,4,1,264>(ACT0, acc, p.b_ea, cs64, l);
  }
  __syncthreads();
  // ---- Phase 2: gather nh -> ACT3 [32][264] ; node_hidden -> ACT1 ----
  {
    int row = tid >> 3, q = tid & 7;
    int idx = p.nbrl[n * KK + row];
    const unsigned short* src = p.nhb + (size_t)idx * HH + q * 32;
    unsigned short* d = ACT3 + row * 264 + q * 32;
    #pragma unroll
    for (int j = 0; j < 4; ++j) *(bs8*)(d + j * 8) = *(const bs8*)(src + j * 8);
  }
  __syncthreads();
  {
    f4 acc[2][4]; zero_acc<2,4>(acc);
    gemm_T<2,4,8,8,264,264,256>(acc, p.wtNH, ACT3, ACT3, cs64, l);
    store_T<2,4,1,264>(ACT1, acc, p.b_nh, cs64, l);
  }
  __syncthreads();
  // ---- Phase 3: LN1e(ef) -> ACT3 ; edge_hidden -> VTB ([32][264]) ----
  {
    int row = tid >> 3, q = tid & 7;
    const float* src = p.ef + (ebase + row) * HH + q * 32;
    float s = 0.f, ss = 0.f;
    float4 vv[8];
    #pragma unroll
    for (int j = 0; j < 8; ++j) {
      float4 v = ((const float4*)src)[j];
      vv[j] = v;
      s += v.x + v.y + v.z + v.w;
      ss += v.x * v.x + v.y * v.y + v.z * v.z + v.w * v.w;
    }
    s += __shfl_xor(s, 1); ss += __shfl_xor(ss, 1);
    s += __shfl_xor(s, 2); ss += __shfl_xor(ss, 2);
    s += __shfl_xor(s, 4); ss += __shfl_xor(ss, 4);
    float mean = s * (1.f / HH);
    float var = ss * (1.f / HH) - mean * mean;
    float rstd = rsqrtf(var + 1e-5f);
    unsigned short* d = ACT3 + row * 264 + q * 32;
    #pragma unroll
    for (int j = 0; j < 8; ++j) {
      int c = q * 32 + j * 4;
      float4 g = *(const float4*)(p.ln1e_g + c);
      float4 b = *(const float4*)(p.ln1e_b + c);
      float4 v = vv[j];
      unsigned short o[4];
      o[0] = f2b((v.x - mean) * rstd * g.x + b.x);
      o[1] = f2b((v.y - mean) * rstd * g.y + b.y);
      o[2] = f2b((v.z - mean) * rstd * g.z + b.z);
      o[3] = f2b((v.w - mean) * rstd * g.w + b.w);
      *(bs4*)(d + j * 4) = *(bs4*)o;
    }
  }
  __syncthreads();
  {
    f4 acc[2][4]; zero_acc<2,4>(acc);
    gemm_T<2,4,8,8,264,264,256>(acc, p.wtEH, ACT3, ACT3, cs64, l);
    store_T<2,4,1,264>(VTB, acc, p.b_eh, cs64, l);
  }
  __syncthreads();
  // ---- Phase 4: gate/cand -> message -> ACT3 ----
  {
    f4 ag[2][4]; zero_acc<2,4>(ag);
    f4 ac[2][4]; zero_acc<2,4>(ac);
    gemm_T<2,4,16,8,264,264,512>(ag, p.wtG, ACT0, ACT1, cs64, l);
    gemm_T<2,4,16,8,264,264,512>(ac, p.wtC, ACT0, ACT1, cs64, l);
    #pragma unroll
    for (int ct = 0; ct < 4; ++ct) {
      f4 bg = *(const f4*)(p.b_gate + cs64 + ct * 16 + lr);
      f4 bc = *(const f4*)(p.b_cand + cs64 + ct * 16 + lr);
      #pragma unroll
      for (int rt = 0; rt < 2; ++rt) {
        bs4 ev = *(const bs4*)(VTB + (rt * 16 + lm) * 264 + cs64 + ct * 16 + lr);
        unsigned short o[4];
        #pragma unroll
        for (int r = 0; r < 4; ++r) {
          float g = sigmoid_f(ag[rt][ct][r] + bg[r]);
          float c = fast_tanh(ac[rt][ct][r] + bc[r]);
          float eh = b2f((unsigned short)ev[r]);
          o[r] = f2b(g * c + (1.f - g) * eh);
        }
        *(bs4*)(ACT3 + (rt * 16 + lm) * 264 + cs64 + ct * 16 + lr) = *(bs4*)o;
      }
    }
  }
  __syncthreads();
  // ---- Phase 5: qkv (q->ACT0, k->ACT1, Vt[256][40]->VTB) ----
  {
    f4 acc[2][4];
    zero_acc<2,4>(acc);
    gemm_T<2,4,8,8,264,264,256>(acc, p.wtIN, ACT3, ACT3, cs64, l);
    store_T<2,4,0,264>(ACT0, acc, p.b_in, cs64, l);
    zero_acc<2,4>(acc);
    gemm_T<2,4,8,8,264,264,256>(acc, p.wtIN + 256 * 256, ACT3, ACT3, cs64, l);
    store_T<2,4,0,264>(ACT1, acc, p.b_in + 256, cs64, l);
    zero_acc<2,4>(acc);
    gemm_T<2,4,8,8,264,264,256>(acc, p.wtIN + 512 * 256, ACT3, ACT3, cs64, l);
    #pragma unroll
    for (int ct = 0; ct < 4; ++ct) {
      f4 bv = *(const f4*)(p.b_in + 512 + cs64 + ct * 16 + lr);
      #pragma unroll
      for (int rt = 0; rt < 2; ++rt)
        #pragma unroll
        for (int r = 0; r < 4; ++r) {
          int d = cs64 + ct * 16 + lr + r;
          VTB[d * 40 + rt * 16 + lm] = f2b(acc[rt][ct][r] + bv[r]);
        }
    }
  }
  __syncthreads();
  // ---- Phase 6: attention (2 heads per wave, sequential) -> ctx -> ACT3 ----
  {
    unsigned short* Pt = RRu + w * 1280;   // [32][40]
    f4 z; z[0] = 0.f; z[1] = 0.f; z[2] = 0.f; z[3] = 0.f;
    #pragma unroll
    for (int hh = 0; hh < 2; ++hh) {
      const int h = w * 2 + hh;
      const int colb = h * 32;
      const float asc = p.ascal[h];
      bs8 kf[2], qf[2];
      #pragma unroll
      for (int kt = 0; kt < 2; ++kt)
        kf[kt] = *(const bs8*)(ACT1 + (kt * 16 + lm) * 264 + colb + lg);
      #pragma unroll
      for (int qt = 0; qt < 2; ++qt)
        qf[qt] = *(const bs8*)(ACT0 + (qt * 16 + lm) * 264 + colb + lg);
      // S^T[k][q] : lane holds q = qt*16+lm, k = kt*16+lr+r
      f4 sc[2][2];
      #pragma unroll
      for (int kt = 0; kt < 2; ++kt)
        #pragma unroll
        for (int qt = 0; qt < 2; ++qt)
          sc[kt][qt] = __builtin_amdgcn_mfma_f32_16x16x32_bf16(kf[kt], qf[qt], z, 0, 0, 0);
      float inv[2];
      #pragma unroll
      for (int qt = 0; qt < 2; ++qt) {
        const int q = qt * 16 + lm;
        float sv[2][4];
        #pragma unroll
        for (int kt = 0; kt < 2; ++kt) {
          f4 av = *(const f4*)(p.ang + ((((size_t)n) * 8 + h) * 32 + q) * 32 + kt * 16 + lr);
          #pragma unroll
          for (int r = 0; r < 4; ++r) {
            int kidx = kt * 16 + lr + r;
            sv[kt][r] = sc[kt][qt][r] * 0.17677669529663687f + av[r] * asc
                      + (kidx < cnt ? 0.f : -1e9f);
          }
        }
        float m = sv[0][0];
        #pragma unroll
        for (int r = 1; r < 4; ++r) m = fmaxf(m, sv[0][r]);
        #pragma unroll
        for (int r = 0; r < 4; ++r) m = fmaxf(m, sv[1][r]);
        m = fmaxf(m, __shfl_xor(m, 16));
        m = fmaxf(m, __shfl_xor(m, 32));
        float e[2][4], sum = 0.f;
        #pragma unroll
        for (int kt = 0; kt < 2; ++kt)
          #pragma unroll
          for (int r = 0; r < 4; ++r) { e[kt][r] = __expf(sv[kt][r] - m); sum += e[kt][r]; }
        sum += __shfl_xor(sum, 16);
        sum += __shfl_xor(sum, 32);
        inv[qt] = 1.f / sum;
        #pragma unroll
        for (int kt = 0; kt < 2; ++kt) {
          unsigned short o[4];
          #pragma unroll
          for (int r = 0; r < 4; ++r) o[r] = f2b(e[kt][r]);
          *(bs4*)(Pt + q * 40 + kt * 16 + lr) = *(bs4*)o;
        }
      }
      // PV: ctx^T[d][q] = mfma(Vt, P)
      bs8 pf[2], vf[2];
      #pragma unroll
      for (int qt = 0; qt < 2; ++qt)
        pf[qt] = *(const bs8*)(Pt + (qt * 16 + lm) * 40 + lg);
      #pragma unroll
      for (int dt = 0; dt < 2; ++dt)
        vf[dt] = *(const bs8*)(VTB + (colb + dt * 16 + lm) * 40 + lg);
      f4 cx[2][2];
      #pragma unroll
      for (int qt = 0; qt < 2; ++qt)
        #pragma unroll
        for (int dt = 0; dt < 2; ++dt)
          cx[qt][dt] = __builtin_amdgcn_mfma_f32_16x16x32_bf16(vf[dt], pf[qt], z, 0, 0, 0);
      #pragma unroll
      for (int qt = 0; qt < 2; ++qt)
        #pragma unroll
        for (int dt = 0; dt < 2; ++dt) {
          unsigned short o[4];
          #pragma unroll
          for (int r = 0; r < 4; ++r) o[r] = f2b(cx[qt][dt][r] * inv[qt]);
          *(bs4*)(ACT3 + (qt * 16 + lm) * 264 + colb + dt * 16 + lr) = *(bs4*)o;
        }
    }
  }
  __syncthreads();
  // ---- Phase 7: eo = ctx @ W_out -> ACT0 ----
  {
    f4 acc[2][4]; zero_acc<2,4>(acc);
    gemm_T<2,4,8,8,264,264,256>(acc, p.wtOUT, ACT3, ACT3, cs64, l);
    store_T<2,4,0,264>(ACT0, acc, p.b_out, cs64, l);
  }
  __syncthreads();
  // ---- Phase 8: alpha aggregation + node path ----
  float* SA  = (float*)(RRu + SA_U);
  float* SNF = (float*)(RRu + SNF_U);
  float* LNP = (float*)(RRu + LNP_U);
  unsigned short* NSTG = RRu + NSTG_U;
  unsigned short* NH1  = RRu + NH1_U;
  {
    int k = tid >> 3, h = tid & 7;
    float aa = 0.f;
    #pragma unroll
    for (int j = 0; j < 8; ++j) {
      bs4 ev = *(const bs4*)(ACT0 + k * 264 + h * 32 + j * 4);
      float4 av = *(const float4*)(p.aw + h * 32 + j * 4);
      aa += b2f((unsigned short)ev[0]) * av.x + b2f((unsigned short)ev[1]) * av.y
          + b2f((unsigned short)ev[2]) * av.z + b2f((unsigned short)ev[3]) * av.w;
    }
    aa = aa > 0.f ? aa : 0.2f * aa;
    if (k >= cnt) aa = -1e9f;
    SA[k * 8 + h] = aa;
  }
  __syncthreads();
  if (tid < 128) {
    int h = tid >> 4, l16 = tid & 15;
    float v0 = SA[l16 * 8 + h], v1 = SA[(l16 + 16) * 8 + h];
    float m = fmaxf(v0, v1);
    m = fmaxf(m, __shfl_xor(m, 1));
    m = fmaxf(m, __shfl_xor(m, 2));
    m = fmaxf(m, __shfl_xor(m, 4));
    m = fmaxf(m, __shfl_xor(m, 8));
    float e0 = __expf(v0 - m), e1 = __expf(v1 - m);
    float s = e0 + e1;
    s += __shfl_xor(s, 1);
    s += __shfl_xor(s, 2);
    s += __shfl_xor(s, 4);
    s += __shfl_xor(s, 8);
    float inv = 1.f / s;
    SA[l16 * 8 + h] = e0 * inv;
    SA[(l16 + 16) * 8 + h] = e1 * inv;
  }
  __syncthreads();
  {
    int c = tid, h = c >> 5;
    float no = 0.f;
    #pragma unroll
    for (int k = 0; k < 32; ++k)
      no = fmaf(SA[k * 8 + h], b2f(ACT0[k * 264 + c]), no);
    float nodef = no + p.nf[(size_t)n * HH + c];
    SNF[c] = nodef;
    float s = nodef, ss = nodef * nodef;
    #pragma unroll
    for (int m = 1; m < 64; m <<= 1) { s += __shfl_xor(s, m); ss += __shfl_xor(ss, m); }
    if (l == 0) { LNP[w * 2] = s; LNP[w * 2 + 1] = ss; }
  }
  __syncthreads();
  {
    int c = tid;
    float S = LNP[0] + LNP[2] + LNP[4] + LNP[6];
    float SS = LNP[1] + LNP[3] + LNP[5] + LNP[7];
    float mean = S * (1.f / HH), var = SS * (1.f / HH) - mean * mean;
    float rstd = rsqrtf(var + 1e-5f);
    NSTG[c] = f2b((SNF[c] - mean) * rstd * p.ln2n_g[c] + p.ln2n_b[c]);
  }
  __syncthreads();
  {
    // node FFN1 via broadcast-B MFMA (M=1)
    f4 a1[8];
    #pragma unroll
    for (int ct = 0; ct < 8; ++ct) { a1[ct][0]=0.f; a1[ct][1]=0.f; a1[ct][2]=0.f; a1[ct][3]=0.f; }
    #pragma unroll
    for (int kb = 0; kb < 8; ++kb) {
      bs8 bfr = *(const bs8*)(NSTG + kb * 32 + lg);
      #pragma unroll
      for (int ct = 0; ct < 8; ++ct) {
        bs8 wfr = *(const bs8*)(p.wtN1 + (size_t)(w * 128 + ct * 16 + lm) * 256 + kb * 32 + lg);
        a1[ct] = __builtin_amdgcn_mfma_f32_16x16x32_bf16(wfr, bfr, a1[ct], 0, 0, 0);
      }
    }
    if (lm == 0) {
      #pragma unroll
      for (int ct = 0; ct < 8; ++ct) {
        int col = w * 128 + ct * 16 + lr;
        f4 bv = *(const f4*)(p.bn1 + col);
        unsigned short o[4];
        #pragma unroll
        for (int r = 0; r < 4; ++r) o[r] = f2b(gelu_f(a1[ct][r] + bv[r]));
        *(bs4*)(NH1 + col) = *(bs4*)o;
      }
    }
  }
  __syncthreads();
  {
    // node FFN2 + residual -> on
    f4 a2[4];
    #pragma unroll
    for (int ct = 0; ct < 4; ++ct) { a2[ct][0]=0.f; a2[ct][1]=0.f; a2[ct][2]=0.f; a2[ct][3]=0.f; }
    #pragma unroll
    for (int kb = 0; kb < 16; ++kb) {
      bs8 bfr = *(const bs8*)(NH1 + kb * 32 + lg);
      #pragma unroll
      for (int ct = 0; ct < 4; ++ct) {
        bs8 wfr = *(const bs8*)(p.wtN2 + (size_t)(cs64 + ct * 16 + lm) * 512 + kb * 32 + lg);
        a2[ct] = __builtin_amdgcn_mfma_f32_16x16x32_bf16(wfr, bfr, a2[ct], 0, 0, 0);
      }
    }
    if (lm == 0) {
      #pragma unroll
      for (int ct = 0; ct < 4; ++ct) {
        int col = cs64 + ct * 16 + lr;
        f4 bv = *(const f4*)(p.bn2 + col);
        float4 o;
        o.x = a2[ct][0] + bv[0] + SNF[col];
        o.y = a2[ct][1] + bv[1] + SNF[col + 1];
        o.z = a2[ct][2] + bv[2] + SNF[col + 2];
        o.w = a2[ct][3] + bv[3] + SNF[col + 3];
        *(float4*)(p.on + (size_t)n * HH + col) = o;
      }
    }
  }
  __syncthreads();
  // ---- Phase 9: edge residual + LN2e -> ACT3 ; edge FFN -> oe ----
  {
    int row = tid >> 3, q = tid & 7;
    const float* efs = p.ef + (ebase + row) * HH + q * 32;
    unsigned short* eor = ACT0 + row * 264 + q * 32;
    float s = 0.f, ss = 0.f;
    float xv[32];
    #pragma unroll
    for (int j = 0; j < 8; ++j) {
      float4 e = ((const float4*)efs)[j];
      bs4 ov = *(const bs4*)(eor + j * 4);
      float x0 = e.x + b2f((unsigned short)ov[0]);
      float x1 = e.y + b2f((unsigned short)ov[1]);
      float x2 = e.z + b2f((unsigned short)ov[2]);
      float x3 = e.w + b2f((unsigned short)ov[3]);
      xv[j * 4] = x0; xv[j * 4 + 1] = x1; xv[j * 4 + 2] = x2; xv[j * 4 + 3] = x3;
      unsigned short o[4] = { f2b(x0), f2b(x1), f2b(x2), f2b(x3) };
      *(bs4*)(eor + j * 4) = *(bs4*)o;
      s += x0 + x1 + x2 + x3;
      ss += x0 * x0 + x1 * x1 + x2 * x2 + x3 * x3;
    }
    s += __shfl_xor(s, 1); ss += __shfl_xor(ss, 1);
    s += __shfl_xor(s, 2); ss += __shfl_xor(ss, 2);
    s += __shfl_xor(s, 4); ss += __shfl_xor(ss, 4);
    float mean = s * (1.f / HH);
    float var = ss * (1.f / HH) - mean * mean;
    float rstd = rsqrtf(var + 1e-5f);
    unsigned short* d = ACT3 + row * 264 + q * 32;
    #pragma unroll
    for (int j = 0; j < 8; ++j) {
      int c = q * 32 + j * 4;
      float4 g = *(const float4*)(p.ln2e_g + c);
      float4 b = *(const float4*)(p.ln2e_b + c);
      unsigned short o[4];
      o[0] = f2b((xv[j * 4] - mean) * rstd * g.x + b.x);
      o[1] = f2b((xv[j * 4 + 1] - mean) * rstd * g.y + b.y);
      o[2] = f2b((xv[j * 4 + 2] - mean) * rstd * g.z + b.z);
      o[3] = f2b((xv[j * 4 + 3] - mean) * rstd * g.w + b.w);
      *(bs4*)(d + j * 4) = *(bs4*)o;
    }
  }
  __syncthreads();
  {
    unsigned short* HID = ACT1;   // [32][520] spans ACT1+VTB
    f4 acc8[2][8]; zero_acc<2,8>(acc8);
    gemm_T<2,8,8,8,264,264,256>(acc8, p.wtE1, ACT3, ACT3, w * 128, l);
    store_T<2,8,1,520>(HID, acc8, p.be1, w * 128, l);
  }
  __syncthreads();
  {
    unsigned short* HID = ACT1;
    f4 acc[2][4]; zero_acc<2,4>(acc);
    gemm_T<2,4,16,16,520,520,512>(acc, p.wtE2, HID, HID, cs64, l);
    #pragma unroll
    for (int ct = 0; ct < 4; ++ct) {
      f4 bv = *(const f4*)(p.be2 + cs64 + ct * 16 + lr);
      #pragma unroll
      for (int rt = 0; rt < 2; ++rt) {
        int row = rt * 16 + lm;
        bs4 rv = *(const bs4*)(ACT0 + row * 264 + cs64 + ct * 16 + lr);
        float4 o;
        o.x = acc[rt][ct][0] + bv[0] + b2f((unsigned short)rv[0]);
        o.y = acc[rt][ct][1] + bv[1] + b2f((unsigned short)rv[1]);
        o.z = acc[rt][ct][2] + bv[2] + b2f((unsigned short)rv[2]);
        o.w = acc[rt][ct][3] + bv[3] + b2f((unsigned short)rv[3]);
        *(float4*)(p.oe + (ebase + row) * HH + cs64 + ct * 16 + lr) = o;
      }
    }
  }
}

extern "C" void kernel_launch(void* const* d_in, const int* in_sizes, int n_in,
                              void* d_out, int out_size, void* d_ws, size_t ws_size,
                              hipStream_t stream)
{
  P p;
  p.nf     = (const float*)d_in[0];
  p.ef     = (const float*)d_in[1];
  p.ear    = (const float*)d_in[2];
  p.ang    = (const float*)d_in[3];
  const float* ln1n_g = (const float*)d_in[4];
  const float* ln1n_b = (const float*)d_in[5];
  p.ln1e_g = (const float*)d_in[6];  p.ln1e_b = (const float*)d_in[7];
  const float* W_ea   = (const float*)d_in[8];  p.b_ea   = (const float*)d_in[9];
  const float* W_nh   = (const float*)d_in[10]; p.b_nh   = (const float*)d_in[11];
  const float* W_eh   = (const float*)d_in[12]; p.b_eh   = (const float*)d_in[13];
  const float* W_gate = (const float*)d_in[14]; p.b_gate = (const float*)d_in[15];
  const float* W_cand = (const float*)d_in[16]; p.b_cand = (const float*)d_in[17];
  p.ascal  = (const float*)d_in[18];
  const float* W_in   = (const float*)d_in[19]; p.b_in   = (const float*)d_in[20];
  const float* W_out  = (const float*)d_in[21]; p.b_out  = (const float*)d_in[22];
  p.aw     = (const float*)d_in[23];
  p.ln2n_g = (const float*)d_in[24]; p.ln2n_b = (const float*)d_in[25];
  p.ln2e_g = (const float*)d_in[26]; p.ln2e_b = (const float*)d_in[27];
  const float* Wn1 = (const float*)d_in[28]; p.bn1 = (const float*)d_in[29];
  const float* Wn2 = (const float*)d_in[30]; p.bn2 = (const float*)d_in[31];
  const float* We1 = (const float*)d_in[32]; p.be1 = (const float*)d_in[33];
  const float* We2 = (const float*)d_in[34]; p.be2 = (const float*)d_in[35];
  p.nbrl   = (const int*)d_in[36];
  p.nbrc   = (const int*)d_in[37];
  p.on     = (float*)d_out;
  p.oe     = (float*)d_out + (size_t)NN * HH;

  size_t off = 0;
  auto alloc = [&](size_t elems) {
    unsigned short* q = (unsigned short*)((char*)d_ws + off);
    off += elems * 2;
    return q;
  };
  unsigned short* nhb = alloc((size_t)NN * HH);
  unsigned short* wtEA  = alloc(256 * 128);
  unsigned short* wtNH  = alloc(256 * 256);
  unsigned short* wtEH  = alloc(256 * 256);
  unsigned short* wtG   = alloc(256 * 512);
  unsigned short* wtC   = alloc(256 * 512);
  unsigned short* wtIN  = alloc(768 * 256);
  unsigned short* wtOUT = alloc(256 * 256);
  unsigned short* wtN1  = alloc(512 * 256);
  unsigned short* wtN2  = alloc(256 * 512);
  unsigned short* wtE1  = alloc(512 * 256);
  unsigned short* wtE2  = alloc(256 * 512);
  p.nhb = nhb;
  p.wtEA = wtEA; p.wtNH = wtNH; p.wtEH = wtEH; p.wtG = wtG; p.wtC = wtC;
  p.wtIN = wtIN; p.wtOUT = wtOUT; p.wtN1 = wtN1; p.wtN2 = wtN2; p.wtE1 = wtE1; p.wtE2 = wtE2;

  node_ln_bf16<<<NN / 4, 256, 0, stream>>>((const float*)d_in[0], ln1n_g, ln1n_b, nhb);

  auto tr = [&](const float* src, unsigned short* dst, int K, int C) {
    wt_transpose<<<dim3(K / 32, C / 32), 256, 0, stream>>>(src, dst, K, C);
  };
  tr(W_ea, wtEA, 128, 256);
  tr(W_nh, wtNH, 256, 256);
  tr(W_eh, wtEH, 256, 256);
  tr(W_gate, wtG, 512, 256);
  tr(W_cand, wtC, 512, 256);
  tr(W_in, wtIN, 256, 768);
  tr(W_out, wtOUT, 256, 256);
  tr(Wn1, wtN1, 256, 512);
  tr(Wn2, wtN2, 512, 256);
  tr(We1, wtE1, 256, 512);
  tr(We2, wtE2, 512, 256);

  (void)hipFuncSetAttribute((const void*)mega_kernel,
                            hipFuncAttributeMaxDynamicSharedMemorySize, LDS_BYTES);
  mega_kernel<<<NN, 256, LDS_BYTES, stream>>>(p);
}

// Round 4
// 2505.372 us; speedup vs baseline: 6.2853x; 1.0129x over previous
//
#include <hip/hip_runtime.h>
#include <math.h>

#define NN 8000
#define KK 32
#define HH 256
#define DE 128

typedef __attribute__((ext_vector_type(8))) short bs8;
typedef __attribute__((ext_vector_type(4))) short bs4;
typedef __attribute__((ext_vector_type(4))) float f4;

// ---- LDS regions (ushort elem offsets), total 40832 elems = 81664 B (2 blocks/CU) ----
#define R0_OFF 0        // 8448: eattr / q / eo / edge_f
#define R1_OFF 8448     // 8448: nhg / ehid / k / ln2e
#define R2_OFF 16896    // 8448: nhid / ctx ; HID[32][520] spans R2+R3
#define R3_OFF 25344    // 10240: ln1e / msg / Vt[256][40]
#define R4_OFF 35584    // 5248: ear[32][136] / Pt 4x[32][40] / node scratch
#define LDS_ELEMS 40832
#define LDS_BYTES (LDS_ELEMS * 2)
// R4 node-scratch sub-offsets (elems)
#define SA_U   0
#define SNF_U  512
#define LNP_U  1024
#define NSTG_U 1088
#define NH1_U  1360

struct P {
  const float *nf, *ef, *ear, *ang;
  const float *ln1e_g, *ln1e_b;
  const float *b_ea, *b_nh, *b_eh, *b_gate, *b_cand;
  const float *ascal, *b_in, *b_out, *aw;
  const float *ln2n_g, *ln2n_b, *ln2e_g, *ln2e_b;
  const float *bn1, *bn2, *be1, *be2;
  const int *nbrl, *nbrc;
  const unsigned short *nhb;
  const unsigned short *wtEA, *wtNH, *wtEH, *wtG, *wtC, *wtIN, *wtOUT, *wtN1, *wtN2, *wtE1, *wtE2;
  float *on, *oe;
};

__device__ __forceinline__ unsigned short f2b(float f) {
  unsigned int u = __float_as_uint(f);
  unsigned int r = (u + 0x7fffu + ((u >> 16) & 1u)) >> 16;
  return (unsigned short)r;
}
__device__ __forceinline__ float b2f(unsigned short u) {
  return __uint_as_float(((unsigned int)u) << 16);
}
__device__ __forceinline__ unsigned int cvt_pk_bf16(float lo, float hi) {
  unsigned int r;
  asm("v_cvt_pk_bf16_f32 %0, %1, %2" : "=v"(r) : "v"(lo), "v"(hi));
  return r;
}
__device__ __forceinline__ bs4 pack4(float a, float b, float c, float d) {
  union { unsigned int u[2]; bs4 v; } x;
  x.u[0] = cvt_pk_bf16(a, b);
  x.u[1] = cvt_pk_bf16(c, d);
  return x.v;
}
__device__ __forceinline__ float fast_tanh(float x) {
  x = fminf(fmaxf(x, -12.f), 12.f);
  float e = __expf(2.f * x);
  return (e - 1.f) / (e + 1.f);
}
__device__ __forceinline__ float gelu_f(float x) {
  return 0.5f * x * (1.f + fast_tanh(0.7978845608f * (x + 0.044715f * x * x * x)));
}
__device__ __forceinline__ float sigmoid_f(float x) {
  return 1.f / (1.f + __expf(-x));
}

// prefetch first PRE k-slices of weight fragments (before a barrier)
template<int NCT, int PRE, int KW>
__device__ __forceinline__ void loadW(bs8 wpre[PRE][NCT],
    const unsigned short* __restrict__ wt, int cs, int l)
{
  const int lm = l & 15;
  const int lg = (l >> 4) << 3;
  #pragma unroll
  for (int kb = 0; kb < PRE; ++kb)
    #pragma unroll
    for (int ct = 0; ct < NCT; ++ct)
      wpre[kb][ct] = *(const bs8*)(wt + (size_t)(cs + ct * 16 + lm) * KW + kb * 32 + lg);
}

// D^T: acc[rt][ct] = mfma(W_frag, act_frag); lane holds act_row = rt*16+(l&15),
// outcols = cs + ct*16 + (l>>4)*4 + r. First PRE k-slices of W come from wpre.
template<int RT, int NCT, int KB, int PRE, int KSPL, int LDA0, int LDA1, int KW>
__device__ __forceinline__ void gemm_pre(f4 acc[RT][NCT],
    const bs8 wpre[PRE][NCT],
    const unsigned short* __restrict__ wt,
    const unsigned short* __restrict__ A0,
    const unsigned short* __restrict__ A1,
    int cs, int l)
{
  const int lm = l & 15;
  const int lg = (l >> 4) << 3;
  #pragma unroll
  for (int kb = 0; kb < KB; ++kb) {
    bs8 wfr[NCT];
    #pragma unroll
    for (int ct = 0; ct < NCT; ++ct) {
      if (kb < PRE) wfr[ct] = wpre[kb][ct];
      else wfr[ct] = *(const bs8*)(wt + (size_t)(cs + ct * 16 + lm) * KW + kb * 32 + lg);
    }
    bs8 afr[RT];
    #pragma unroll
    for (int rt = 0; rt < RT; ++rt) {
      if (kb < KSPL)
        afr[rt] = *(const bs8*)(A0 + (rt * 16 + lm) * LDA0 + kb * 32 + lg);
      else
        afr[rt] = *(const bs8*)(A1 + (rt * 16 + lm) * LDA1 + (kb - KSPL) * 32 + lg);
    }
    #pragma unroll
    for (int rt = 0; rt < RT; ++rt)
      #pragma unroll
      for (int ct = 0; ct < NCT; ++ct)
        acc[rt][ct] = __builtin_amdgcn_mfma_f32_16x16x32_bf16(wfr[ct], afr[rt], acc[rt][ct], 0, 0, 0);
  }
}

template<int RT, int NCT>
__device__ __forceinline__ void zero_acc(f4 acc[RT][NCT]) {
  #pragma unroll
  for (int rt = 0; rt < RT; ++rt)
    #pragma unroll
    for (int ct = 0; ct < NCT; ++ct) {
      acc[rt][ct][0] = 0.f; acc[rt][ct][1] = 0.f; acc[rt][ct][2] = 0.f; acc[rt][ct][3] = 0.f;
    }
}

template<int RT, int NCT, int ACTF, int LDD>
__device__ __forceinline__ void store_T(unsigned short* dst,
    f4 acc[RT][NCT], const float* __restrict__ bias, int cs, int l)
{
  const int lm = l & 15;
  const int lr = (l >> 4) << 2;
  #pragma unroll
  for (int ct = 0; ct < NCT; ++ct) {
    f4 bv = *(const f4*)(bias + cs + ct * 16 + lr);
    #pragma unroll
    for (int rt = 0; rt < RT; ++rt) {
      float v[4];
      #pragma unroll
      for (int r = 0; r < 4; ++r) {
        v[r] = acc[rt][ct][r] + bv[r];
        if (ACTF == 1) v[r] = gelu_f(v[r]);
      }
      *(bs4*)(dst + (rt * 16 + lm) * LDD + cs + ct * 16 + lr) = pack4(v[0], v[1], v[2], v[3]);
    }
  }
}

// ---------- pre-kernels ----------
__global__ void node_ln_bf16(const float* __restrict__ x, const float* __restrict__ g,
                             const float* __restrict__ b, unsigned short* __restrict__ y)
{
  int row = blockIdx.x * 4 + (threadIdx.x >> 6);
  int lane = threadIdx.x & 63;
  float4 v = ((const float4*)(x + (size_t)row * HH))[lane];
  float s = v.x + v.y + v.z + v.w;
  float ss = v.x * v.x + v.y * v.y + v.z * v.z + v.w * v.w;
  #pragma unroll
  for (int m = 1; m < 64; m <<= 1) { s += __shfl_xor(s, m); ss += __shfl_xor(ss, m); }
  float mean = s * (1.f / HH);
  float var = ss * (1.f / HH) - mean * mean;
  float rstd = rsqrtf(var + 1e-5f);
  float4 gg = ((const float4*)g)[lane];
  float4 bb = ((const float4*)b)[lane];
  *(bs4*)(y + (size_t)row * HH + lane * 4) =
      pack4((v.x - mean) * rstd * gg.x + bb.x, (v.y - mean) * rstd * gg.y + bb.y,
            (v.z - mean) * rstd * gg.z + bb.z, (v.w - mean) * rstd * gg.w + bb.w);
}

__global__ void wt_transpose(const float* __restrict__ src, unsigned short* __restrict__ dst,
                             int K, int C)
{
  __shared__ float tile[32][33];
  int tx = threadIdx.x & 31, ty = threadIdx.x >> 5;
  int bk = blockIdx.x, bc = blockIdx.y;
  #pragma unroll
  for (int i = 0; i < 4; ++i)
    tile[ty + i * 8][tx] = src[(size_t)(bk * 32 + ty + i * 8) * C + bc * 32 + tx];
  __syncthreads();
  #pragma unroll
  for (int i = 0; i < 4; ++i)
    dst[(size_t)(bc * 32 + ty + i * 8) * K + bk * 32 + tx] = f2b(tile[tx][ty + i * 8]);
}

// ---------- mega kernel: 1 node per block, 2 blocks/CU ----------
__launch_bounds__(256, 2)
__global__ void mega_kernel(P p)
{
  extern __shared__ unsigned short smem[];
  unsigned short* R0 = smem + R0_OFF;
  unsigned short* R1 = smem + R1_OFF;
  unsigned short* R2 = smem + R2_OFF;
  unsigned short* R3 = smem + R3_OFF;
  unsigned short* R4 = smem + R4_OFF;
  unsigned short* HID = smem + R2_OFF;   // [32][520] spans R2+R3

  const int tid = threadIdx.x;
  const int l = tid & 63;
  const int w = tid >> 6;
  const int lm = l & 15;
  const int lg = (l >> 4) << 3;
  const int lr = (l >> 4) << 2;
  const int cs64 = w * 64;
  const int n = blockIdx.x;
  const size_t ebase = (size_t)n * KK;
  const int cnt = p.nbrc[n];

  bs8 wpA[2][4], wpB[2][4];

  // ---- P0: stage ear->R4, nhg->R1, ln1e->R3 ; prefetch EA,NH ----
  {
    int row = tid >> 3, q = tid & 7;
    // ear [32][136]
    const float* src = p.ear + (ebase + row) * DE + q * 16;
    unsigned short* d = R4 + row * 136 + q * 16;
    #pragma unroll
    for (int j = 0; j < 4; ++j) {
      float4 v = ((const float4*)src)[j];
      *(bs4*)(d + j * 4) = pack4(v.x, v.y, v.z, v.w);
    }
    // gather nh [32][264]
    int idx = p.nbrl[n * KK + row];
    const unsigned short* gsrc = p.nhb + (size_t)idx * HH + q * 32;
    unsigned short* gd = R1 + row * 264 + q * 32;
    #pragma unroll
    for (int j = 0; j < 4; ++j) *(bs8*)(gd + j * 8) = *(const bs8*)(gsrc + j * 8);
    // LN1e(ef) [32][264]
    const float* esrc = p.ef + (ebase + row) * HH + q * 32;
    float s = 0.f, ss = 0.f;
    float4 vv[8];
    #pragma unroll
    for (int j = 0; j < 8; ++j) {
      float4 v = ((const float4*)esrc)[j];
      vv[j] = v;
      s += v.x + v.y + v.z + v.w;
      ss += v.x * v.x + v.y * v.y + v.z * v.z + v.w * v.w;
    }
    s += __shfl_xor(s, 1); ss += __shfl_xor(ss, 1);
    s += __shfl_xor(s, 2); ss += __shfl_xor(ss, 2);
    s += __shfl_xor(s, 4); ss += __shfl_xor(ss, 4);
    float mean = s * (1.f / HH);
    float var = ss * (1.f / HH) - mean * mean;
    float rstd = rsqrtf(var + 1e-5f);
    unsigned short* ed = R3 + row * 264 + q * 32;
    #pragma unroll
    for (int j = 0; j < 8; ++j) {
      int c = q * 32 + j * 4;
      float4 g = *(const float4*)(p.ln1e_g + c);
      float4 b = *(const float4*)(p.ln1e_b + c);
      float4 v = vv[j];
      *(bs4*)(ed + j * 4) = pack4((v.x - mean) * rstd * g.x + b.x,
                                  (v.y - mean) * rstd * g.y + b.y,
                                  (v.z - mean) * rstd * g.z + b.z,
                                  (v.w - mean) * rstd * g.w + b.w);
    }
  }
  loadW<4,2,128>(wpA, p.wtEA, cs64, l);
  loadW<4,2,256>(wpB, p.wtNH, cs64, l);
  __syncthreads();
  // ---- P0b: EA -> R0 ; NH -> R2 ; prefetch EH ----
  {
    f4 acc[2][4]; zero_acc<2,4>(acc);
    gemm_pre<2,4,4,2,4,136,136,128>(acc, wpA, p.wtEA, R4, R4, cs64, l);
    store_T<2,4,1,264>(R0, acc, p.b_ea, cs64, l);
    f4 acc2[2][4]; zero_acc<2,4>(acc2);
    gemm_pre<2,4,8,2,8,264,264,256>(acc2, wpB, p.wtNH, R1, R1, cs64, l);
    store_T<2,4,1,264>(R2, acc2, p.b_nh, cs64, l);
  }
  loadW<4,2,256>(wpA, p.wtEH, cs64, l);
  __syncthreads();
  // ---- P1: EH (R3 -> R1) ; prefetch G,C ----
  {
    f4 acc[2][4]; zero_acc<2,4>(acc);
    gemm_pre<2,4,8,2,8,264,264,256>(acc, wpA, p.wtEH, R3, R3, cs64, l);
    store_T<2,4,1,264>(R1, acc, p.b_eh, cs64, l);
  }
  loadW<4,2,512>(wpA, p.wtG, cs64, l);
  loadW<4,2,512>(wpB, p.wtC, cs64, l);
  __syncthreads();
  // ---- P2: gate/cand (R0||R2) + ehid(R1) -> msg -> R3 ; prefetch Q,K ----
  {
    f4 ag[2][4]; zero_acc<2,4>(ag);
    f4 ac[2][4]; zero_acc<2,4>(ac);
    gemm_pre<2,4,16,2,8,264,264,512>(ag, wpA, p.wtG, R0, R2, cs64, l);
    gemm_pre<2,4,16,2,8,264,264,512>(ac, wpB, p.wtC, R0, R2, cs64, l);
    #pragma unroll
    for (int ct = 0; ct < 4; ++ct) {
      f4 bg = *(const f4*)(p.b_gate + cs64 + ct * 16 + lr);
      f4 bc = *(const f4*)(p.b_cand + cs64 + ct * 16 + lr);
      #pragma unroll
      for (int rt = 0; rt < 2; ++rt) {
        bs4 ev = *(const bs4*)(R1 + (rt * 16 + lm) * 264 + cs64 + ct * 16 + lr);
        float o[4];
        #pragma unroll
        for (int r = 0; r < 4; ++r) {
          float g = sigmoid_f(ag[rt][ct][r] + bg[r]);
          float c = fast_tanh(ac[rt][ct][r] + bc[r]);
          o[r] = g * c + (1.f - g) * b2f((unsigned short)ev[r]);
        }
        *(bs4*)(R3 + (rt * 16 + lm) * 264 + cs64 + ct * 16 + lr) = pack4(o[0], o[1], o[2], o[3]);
      }
    }
  }
  loadW<4,2,256>(wpA, p.wtIN, cs64, l);
  loadW<4,2,256>(wpB, p.wtIN + 256 * 256, cs64, l);
  __syncthreads();
  // ---- P3a: Q -> R0, K -> R1, V -> regs ; prefetch OUT ----
  f4 vacc[2][4];
  {
    bs8 wpV[2][4];
    loadW<4,2,256>(wpV, p.wtIN + 512 * 256, cs64, l);
    f4 acc[2][4]; zero_acc<2,4>(acc);
    gemm_pre<2,4,8,2,8,264,264,256>(acc, wpA, p.wtIN, R3, R3, cs64, l);
    store_T<2,4,0,264>(R0, acc, p.b_in, cs64, l);
    zero_acc<2,4>(acc);
    gemm_pre<2,4,8,2,8,264,264,256>(acc, wpB, p.wtIN + 256 * 256, R3, R3, cs64, l);
    store_T<2,4,0,264>(R1, acc, p.b_in + 256, cs64, l);
    zero_acc<2,4>(vacc);
    gemm_pre<2,4,8,2,8,264,264,256>(vacc, wpV, p.wtIN + 512 * 256, R3, R3, cs64, l);
  }
  loadW<4,2,256>(wpA, p.wtOUT, cs64, l);
  __syncthreads();
  // ---- P3b: write Vt[256][40] -> R3 ----
  {
    #pragma unroll
    for (int ct = 0; ct < 4; ++ct) {
      f4 bv = *(const f4*)(p.b_in + 512 + cs64 + ct * 16 + lr);
      #pragma unroll
      for (int rt = 0; rt < 2; ++rt)
        #pragma unroll
        for (int r = 0; r < 4; ++r) {
          int d = cs64 + ct * 16 + lr + r;
          R3[d * 40 + rt * 16 + lm] = f2b(vacc[rt][ct][r] + bv[r]);
        }
    }
  }
  __syncthreads();
  // ---- P4: attention (2 heads/wave) -> ctx -> R2 ----
  {
    unsigned short* Pt = R4 + w * 1280;   // [32][40]
    f4 z; z[0] = 0.f; z[1] = 0.f; z[2] = 0.f; z[3] = 0.f;
    #pragma unroll
    for (int hh = 0; hh < 2; ++hh) {
      const int h = w * 2 + hh;
      const int colb = h * 32;
      const float asc = p.ascal[h];
      bs8 kf[2], qf[2];
      #pragma unroll
      for (int kt = 0; kt < 2; ++kt)
        kf[kt] = *(const bs8*)(R1 + (kt * 16 + lm) * 264 + colb + lg);
      #pragma unroll
      for (int qt = 0; qt < 2; ++qt)
        qf[qt] = *(const bs8*)(R0 + (qt * 16 + lm) * 264 + colb + lg);
      f4 sc[2][2];
      #pragma unroll
      for (int kt = 0; kt < 2; ++kt)
        #pragma unroll
        for (int qt = 0; qt < 2; ++qt)
          sc[kt][qt] = __builtin_amdgcn_mfma_f32_16x16x32_bf16(kf[kt], qf[qt], z, 0, 0, 0);
      float inv[2];
      #pragma unroll
      for (int qt = 0; qt < 2; ++qt) {
        const int q = qt * 16 + lm;
        float sv[2][4];
        #pragma unroll
        for (int kt = 0; kt < 2; ++kt) {
          f4 av = *(const f4*)(p.ang + ((((size_t)n) * 8 + h) * 32 + q) * 32 + kt * 16 + lr);
          #pragma unroll
          for (int r = 0; r < 4; ++r) {
            int kidx = kt * 16 + lr + r;
            sv[kt][r] = sc[kt][qt][r] * 0.17677669529663687f + av[r] * asc
                      + (kidx < cnt ? 0.f : -1e9f);
          }
        }
        float m = sv[0][0];
        #pragma unroll
        for (int r = 1; r < 4; ++r) m = fmaxf(m, sv[0][r]);
        #pragma unroll
        for (int r = 0; r < 4; ++r) m = fmaxf(m, sv[1][r]);
        m = fmaxf(m, __shfl_xor(m, 16));
        m = fmaxf(m, __shfl_xor(m, 32));
        float e[2][4], sum = 0.f;
        #pragma unroll
        for (int kt = 0; kt < 2; ++kt)
          #pragma unroll
          for (int r = 0; r < 4; ++r) { e[kt][r] = __expf(sv[kt][r] - m); sum += e[kt][r]; }
        sum += __shfl_xor(sum, 16);
        sum += __shfl_xor(sum, 32);
        inv[qt] = 1.f / sum;
        *(bs4*)(Pt + q * 40 + lr)      = pack4(e[0][0], e[0][1], e[0][2], e[0][3]);
        *(bs4*)(Pt + q * 40 + 16 + lr) = pack4(e[1][0], e[1][1], e[1][2], e[1][3]);
      }
      bs8 pf[2], vf[2];
      #pragma unroll
      for (int qt = 0; qt < 2; ++qt)
        pf[qt] = *(const bs8*)(Pt + (qt * 16 + lm) * 40 + lg);
      #pragma unroll
      for (int dt = 0; dt < 2; ++dt)
        vf[dt] = *(const bs8*)(R3 + (colb + dt * 16 + lm) * 40 + lg);
      f4 cx[2][2];
      #pragma unroll
      for (int qt = 0; qt < 2; ++qt)
        #pragma unroll
        for (int dt = 0; dt < 2; ++dt)
          cx[qt][dt] = __builtin_amdgcn_mfma_f32_16x16x32_bf16(vf[dt], pf[qt], z, 0, 0, 0);
      #pragma unroll
      for (int qt = 0; qt < 2; ++qt)
        #pragma unroll
        for (int dt = 0; dt < 2; ++dt)
          *(bs4*)(R2 + (qt * 16 + lm) * 264 + colb + dt * 16 + lr) =
              pack4(cx[qt][dt][0] * inv[qt], cx[qt][dt][1] * inv[qt],
                    cx[qt][dt][2] * inv[qt], cx[qt][dt][3] * inv[qt]);
    }
  }
  __syncthreads();
  // ---- P5: eo = ctx @ W_out -> R0 ----
  {
    f4 acc[2][4]; zero_acc<2,4>(acc);
    gemm_pre<2,4,8,2,8,264,264,256>(acc, wpA, p.wtOUT, R2, R2, cs64, l);
    store_T<2,4,0,264>(R0, acc, p.b_out, cs64, l);
  }
  __syncthreads();
  // ---- P6: alpha aggregation + node path + edge residual/LN2e ----
  float* SA  = (float*)(R4 + SA_U);
  float* SNF = (float*)(R4 + SNF_U);
  float* LNP = (float*)(R4 + LNP_U);
  unsigned short* NSTG = R4 + NSTG_U;
  unsigned short* NH1  = R4 + NH1_U;
  {
    int k = tid >> 3, h = tid & 7;
    float aa = 0.f;
    #pragma unroll
    for (int j = 0; j < 8; ++j) {
      bs4 ev = *(const bs4*)(R0 + k * 264 + h * 32 + j * 4);
      float4 av = *(const float4*)(p.aw + h * 32 + j * 4);
      aa += b2f((unsigned short)ev[0]) * av.x + b2f((unsigned short)ev[1]) * av.y
          + b2f((unsigned short)ev[2]) * av.z + b2f((unsigned short)ev[3]) * av.w;
    }
    aa = aa > 0.f ? aa : 0.2f * aa;
    if (k >= cnt) aa = -1e9f;
    SA[k * 8 + h] = aa;
  }
  __syncthreads();
  if (tid < 128) {
    int h = tid >> 4, l16 = tid & 15;
    float v0 = SA[l16 * 8 + h], v1 = SA[(l16 + 16) * 8 + h];
    float m = fmaxf(v0, v1);
    m = fmaxf(m, __shfl_xor(m, 1));
    m = fmaxf(m, __shfl_xor(m, 2));
    m = fmaxf(m, __shfl_xor(m, 4));
    m = fmaxf(m, __shfl_xor(m, 8));
    float e0 = __expf(v0 - m), e1 = __expf(v1 - m);
    float s = e0 + e1;
    s += __shfl_xor(s, 1);
    s += __shfl_xor(s, 2);
    s += __shfl_xor(s, 4);
    s += __shfl_xor(s, 8);
    float inv = 1.f / s;
    SA[l16 * 8 + h] = e0 * inv;
    SA[(l16 + 16) * 8 + h] = e1 * inv;
  }
  __syncthreads();
  {
    int c = tid, h = c >> 5;
    float no = 0.f;
    #pragma unroll
    for (int k = 0; k < 32; ++k)
      no = fmaf(SA[k * 8 + h], b2f(R0[k * 264 + c]), no);
    float nodef = no + p.nf[(size_t)n * HH + c];
    SNF[c] = nodef;
    float s = nodef, ss = nodef * nodef;
    #pragma unroll
    for (int m = 1; m < 64; m <<= 1) { s += __shfl_xor(s, m); ss += __shfl_xor(ss, m); }
    if (l == 0) { LNP[w * 2] = s; LNP[w * 2 + 1] = ss; }
  }
  __syncthreads();
  {
    int c = tid;
    float S = LNP[0] + LNP[2] + LNP[4] + LNP[6];
    float SS = LNP[1] + LNP[3] + LNP[5] + LNP[7];
    float mean = S * (1.f / HH), var = SS * (1.f / HH) - mean * mean;
    float rstd = rsqrtf(var + 1e-5f);
    NSTG[c] = f2b((SNF[c] - mean) * rstd * p.ln2n_g[c] + p.ln2n_b[c]);
  }
  // edge residual + LN2e (R0 updated in place -> edge_f ; ln2e -> R1)
  {
    int row = tid >> 3, q = tid & 7;
    const float* efs = p.ef + (ebase + row) * HH + q * 32;
    unsigned short* eor = R0 + row * 264 + q * 32;
    float s = 0.f, ss = 0.f;
    float xv[32];
    #pragma unroll
    for (int j = 0; j < 8; ++j) {
      float4 e = ((const float4*)efs)[j];
      bs4 ov = *(const bs4*)(eor + j * 4);
      float x0 = e.x + b2f((unsigned short)ov[0]);
      float x1 = e.y + b2f((unsigned short)ov[1]);
      float x2 = e.z + b2f((unsigned short)ov[2]);
      float x3 = e.w + b2f((unsigned short)ov[3]);
      xv[j * 4] = x0; xv[j * 4 + 1] = x1; xv[j * 4 + 2] = x2; xv[j * 4 + 3] = x3;
      *(bs4*)(eor + j * 4) = pack4(x0, x1, x2, x3);
      s += x0 + x1 + x2 + x3;
      ss += x0 * x0 + x1 * x1 + x2 * x2 + x3 * x3;
    }
    s += __shfl_xor(s, 1); ss += __shfl_xor(ss, 1);
    s += __shfl_xor(s, 2); ss += __shfl_xor(ss, 2);
    s += __shfl_xor(s, 4); ss += __shfl_xor(ss, 4);
    float mean = s * (1.f / HH);
    float var = ss * (1.f / HH) - mean * mean;
    float rstd = rsqrtf(var + 1e-5f);
    unsigned short* d = R1 + row * 264 + q * 32;
    #pragma unroll
    for (int j = 0; j < 8; ++j) {
      int c = q * 32 + j * 4;
      float4 g = *(const float4*)(p.ln2e_g + c);
      float4 b = *(const float4*)(p.ln2e_b + c);
      *(bs4*)(d + j * 4) = pack4((xv[j * 4] - mean) * rstd * g.x + b.x,
                                 (xv[j * 4 + 1] - mean) * rstd * g.y + b.y,
                                 (xv[j * 4 + 2] - mean) * rstd * g.z + b.z,
                                 (xv[j * 4 + 3] - mean) * rstd * g.w + b.w);
    }
  }
  __syncthreads();
  {
    // node FFN1 (broadcast-B MFMA, M=1)
    f4 a1[8];
    #pragma unroll
    for (int ct = 0; ct < 8; ++ct) { a1[ct][0]=0.f; a1[ct][1]=0.f; a1[ct][2]=0.f; a1[ct][3]=0.f; }
    #pragma unroll
    for (int kb = 0; kb < 8; ++kb) {
      bs8 bfr = *(const bs8*)(NSTG + kb * 32 + lg);
      #pragma unroll
      for (int ct = 0; ct < 8; ++ct) {
        bs8 wfr = *(const bs8*)(p.wtN1 + (size_t)(w * 128 + ct * 16 + lm) * 256 + kb * 32 + lg);
        a1[ct] = __builtin_amdgcn_mfma_f32_16x16x32_bf16(wfr, bfr, a1[ct], 0, 0, 0);
      }
    }
    if (lm == 0) {
      #pragma unroll
      for (int ct = 0; ct < 8; ++ct) {
        int col = w * 128 + ct * 16 + lr;
        f4 bv = *(const f4*)(p.bn1 + col);
        *(bs4*)(NH1 + col) = pack4(gelu_f(a1[ct][0] + bv[0]), gelu_f(a1[ct][1] + bv[1]),
                                   gelu_f(a1[ct][2] + bv[2]), gelu_f(a1[ct][3] + bv[3]));
      }
    }
  }
  __syncthreads();
  bs8 wpE1[2][8];
  {
    // node FFN2 + residual -> on
    f4 a2[4];
    #pragma unroll
    for (int ct = 0; ct < 4; ++ct) { a2[ct][0]=0.f; a2[ct][1]=0.f; a2[ct][2]=0.f; a2[ct][3]=0.f; }
    #pragma unroll
    for (int kb = 0; kb < 16; ++kb) {
      bs8 bfr = *(const bs8*)(NH1 + kb * 32 + lg);
      #pragma unroll
      for (int ct = 0; ct < 4; ++ct) {
        bs8 wfr = *(const bs8*)(p.wtN2 + (size_t)(cs64 + ct * 16 + lm) * 512 + kb * 32 + lg);
        a2[ct] = __builtin_amdgcn_mfma_f32_16x16x32_bf16(wfr, bfr, a2[ct], 0, 0, 0);
      }
    }
    if (lm == 0) {
      #pragma unroll
      for (int ct = 0; ct < 4; ++ct) {
        int col = cs64 + ct * 16 + lr;
        f4 bv = *(const f4*)(p.bn2 + col);
        float4 o;
        o.x = a2[ct][0] + bv[0] + SNF[col];
        o.y = a2[ct][1] + bv[1] + SNF[col + 1];
        o.z = a2[ct][2] + bv[2] + SNF[col + 2];
        o.w = a2[ct][3] + bv[3] + SNF[col + 3];
        *(float4*)(p.on + (size_t)n * HH + col) = o;
      }
    }
  }
  loadW<8,2,256>(wpE1, p.wtE1, w * 128, l);
  __syncthreads();
  // ---- P7: E1 (R1 -> HID [32][520]) ; prefetch E2 ----
  {
    f4 acc8[2][8]; zero_acc<2,8>(acc8);
    gemm_pre<2,8,8,2,8,264,264,256>(acc8, wpE1, p.wtE1, R1, R1, w * 128, l);
    store_T<2,8,1,520>(HID, acc8, p.be1, w * 128, l);
  }
  loadW<4,2,512>(wpB, p.wtE2, cs64, l);
  __syncthreads();
  // ---- P8: E2 + residual -> oe ----
  {
    f4 acc[2][4]; zero_acc<2,4>(acc);
    gemm_pre<2,4,16,2,16,520,520,512>(acc, wpB, p.wtE2, HID, HID, cs64, l);
    #pragma unroll
    for (int ct = 0; ct < 4; ++ct) {
      f4 bv = *(const f4*)(p.be2 + cs64 + ct * 16 + lr);
      #pragma unroll
      for (int rt = 0; rt < 2; ++rt) {
        int row = rt * 16 + lm;
        bs4 rv = *(const bs4*)(R0 + row * 264 + cs64 + ct * 16 + lr);
        float4 o;
        o.x = acc[rt][ct][0] + bv[0] + b2f((unsigned short)rv[0]);
        o.y = acc[rt][ct][1] + bv[1] + b2f((unsigned short)rv[1]);
        o.z = acc[rt][ct][2] + bv[2] + b2f((unsigned short)rv[2]);
        o.w = acc[rt][ct][3] + bv[3] + b2f((unsigned short)rv[3]);
        *(float4*)(p.oe + (ebase + row) * HH + cs64 + ct * 16 + lr) = o;
      }
    }
  }
}

extern "C" void kernel_launch(void* const* d_in, const int* in_sizes, int n_in,
                              void* d_out, int out_size, void* d_ws, size_t ws_size,
                              hipStream_t stream)
{
  P p;
  p.nf     = (const float*)d_in[0];
  p.ef     = (const float*)d_in[1];
  p.ear    = (const float*)d_in[2];
  p.ang    = (const float*)d_in[3];
  const float* ln1n_g = (const float*)d_in[4];
  const float* ln1n_b = (const float*)d_in[5];
  p.ln1e_g = (const float*)d_in[6];  p.ln1e_b = (const float*)d_in[7];
  const float* W_ea   = (const float*)d_in[8];  p.b_ea   = (const float*)d_in[9];
  const float* W_nh   = (const float*)d_in[10]; p.b_nh   = (const float*)d_in[11];
  const float* W_eh   = (const float*)d_in[12]; p.b_eh   = (const float*)d_in[13];
  const float* W_gate = (const float*)d_in[14]; p.b_gate = (const float*)d_in[15];
  const float* W_cand = (const float*)d_in[16]; p.b_cand = (const float*)d_in[17];
  p.ascal  = (const float*)d_in[18];
  const float* W_in   = (const float*)d_in[19]; p.b_in   = (const float*)d_in[20];
  const float* W_out  = (const float*)d_in[21]; p.b_out  = (const float*)d_in[22];
  p.aw     = (const float*)d_in[23];
  p.ln2n_g = (const float*)d_in[24]; p.ln2n_b = (const float*)d_in[25];
  p.ln2e_g = (const float*)d_in[26]; p.ln2e_b = (const float*)d_in[27];
  const float* Wn1 = (const float*)d_in[28]; p.bn1 = (const float*)d_in[29];
  const float* Wn2 = (const float*)d_in[30]; p.bn2 = (const float*)d_in[31];
  const float* We1 = (const float*)d_in[32]; p.be1 = (const float*)d_in[33];
  const float* We2 = (const float*)d_in[34]; p.be2 = (const float*)d_in[35];
  p.nbrl   = (const int*)d_in[36];
  p.nbrc   = (const int*)d_in[37];
  p.on     = (float*)d_out;
  p.oe     = (float*)d_out + (size_t)NN * HH;

  size_t off = 0;
  auto alloc = [&](size_t elems) {
    unsigned short* q = (unsigned short*)((char*)d_ws + off);
    off += elems * 2;
    return q;
  };
  unsigned short* nhb = alloc((size_t)NN * HH);
  unsigned short* wtEA  = alloc(256 * 128);
  unsigned short* wtNH  = alloc(256 * 256);
  unsigned short* wtEH  = alloc(256 * 256);
  unsigned short* wtG   = alloc(256 * 512);
  unsigned short* wtC   = alloc(256 * 512);
  unsigned short* wtIN  = alloc(768 * 256);
  unsigned short* wtOUT = alloc(256 * 256);
  unsigned short* wtN1  = alloc(512 * 256);
  unsigned short* wtN2  = alloc(256 * 512);
  unsigned short* wtE1  = alloc(512 * 256);
  unsigned short* wtE2  = alloc(256 * 512);
  p.nhb = nhb;
  p.wtEA = wtEA; p.wtNH = wtNH; p.wtEH = wtEH; p.wtG = wtG; p.wtC = wtC;
  p.wtIN = wtIN; p.wtOUT = wtOUT; p.wtN1 = wtN1; p.wtN2 = wtN2; p.wtE1 = wtE1; p.wtE2 = wtE2;

  node_ln_bf16<<<NN / 4, 256, 0, stream>>>((const float*)d_in[0], ln1n_g, ln1n_b, nhb);

  auto tr = [&](const float* src, unsigned short* dst, int K, int C) {
    wt_transpose<<<dim3(K / 32, C / 32), 256, 0, stream>>>(src, dst, K, C);
  };
  tr(W_ea, wtEA, 128, 256);
  tr(W_nh, wtNH, 256, 256);
  tr(W_eh, wtEH, 256, 256);
  tr(W_gate, wtG, 512, 256);
  tr(W_cand, wtC, 512, 256);
  tr(W_in, wtIN, 256, 768);
  tr(W_out, wtOUT, 256, 256);
  tr(Wn1, wtN1, 256, 512);
  tr(Wn2, wtN2, 512, 256);
  tr(We1, wtE1, 256, 512);
  tr(We2, wtE2, 512, 256);

  (void)hipFuncSetAttribute((const void*)mega_kernel,
                            hipFuncAttributeMaxDynamicSharedMemorySize, LDS_BYTES);
  mega_kernel<<<NN, 256, LDS_BYTES, stream>>>(p);
}

// Round 6
// 1618.285 us; speedup vs baseline: 9.7307x; 1.5482x over previous
//
#include <hip/hip_runtime.h>
#include <math.h>

#define NN 8000
#define KK 32
#define HH 256
#define DE 128
#define NODES 4
#define THREADS 512
#define BIGLD 536
#define LDS_BYTES (128 * BIGLD * 2)

typedef __attribute__((ext_vector_type(8))) short bs8;
typedef __attribute__((ext_vector_type(4))) short bs4;
typedef __attribute__((ext_vector_type(4))) float f4;

#define LGK_FENCE() do { asm volatile("s_waitcnt lgkmcnt(0)" ::: "memory"); __builtin_amdgcn_sched_barrier(0); } while (0)

struct P {
  const float *nf, *ef, *ear, *ang;
  const float *ln1e_g, *ln1e_b;
  const float *b_ea, *b_nh, *b_eh, *b_gate, *b_cand;
  const float *ascal, *b_in, *b_out, *aw;
  const float *ln2n_g, *ln2n_b, *ln2e_g, *ln2e_b;
  const float *bn1, *bn2, *be1, *be2;
  const int *nbrl, *nbrc;
  const unsigned short *nhb;
  const unsigned short *wtEA, *wtNH, *wtEH, *wtG, *wtC, *wtIN, *wtOUT, *wtN1, *wtN2, *wtE1, *wtE2;
  float *on, *oe;
};

__device__ __forceinline__ unsigned short f2b(float f) {
  unsigned int u = __float_as_uint(f);
  unsigned int r = (u + 0x7fffu + ((u >> 16) & 1u)) >> 16;
  return (unsigned short)r;
}
__device__ __forceinline__ float b2f(unsigned short u) {
  return __uint_as_float(((unsigned int)u) << 16);
}
__device__ __forceinline__ unsigned int cvt_pk_bf16(float lo, float hi) {
  unsigned int r;
  asm("v_cvt_pk_bf16_f32 %0, %1, %2" : "=v"(r) : "v"(lo), "v"(hi));
  return r;
}
__device__ __forceinline__ bs4 pack4(float a, float b, float c, float d) {
  union { unsigned int u[2]; bs4 v; } x;
  x.u[0] = cvt_pk_bf16(a, b);
  x.u[1] = cvt_pk_bf16(c, d);
  return x.v;
}
__device__ __forceinline__ float fast_tanh(float x) {
  x = fminf(fmaxf(x, -12.f), 12.f);
  float e = __expf(2.f * x);
  return (e - 1.f) / (e + 1.f);
}
__device__ __forceinline__ float gelu_f(float x) {
  return 0.5f * x * (1.f + fast_tanh(0.7978845608f * (x + 0.044715f * x * x * x)));
}
__device__ __forceinline__ float sigmoid_f(float x) {
  return 1.f / (1.f + __expf(-x));
}

// acc[rt][ct] = mfma(Wfrag, Afrag): out row = rt*16+(l&15) (= A row),
// out col = cs + ct*16 + (l>>4)*4 + r. A in LDS, row stride BIGLD. W [outcol][KW].
template<int RT, int NCT, int KB, int KW>
__device__ __forceinline__ void gemmB(f4 acc[RT][NCT],
    const unsigned short* __restrict__ wt,
    const unsigned short* __restrict__ A, int cs, int l)
{
  const int lm = l & 15;
  const int lg = (l >> 4) << 3;
  #pragma unroll
  for (int kb = 0; kb < KB; ++kb) {
    bs8 wfr[NCT];
    #pragma unroll
    for (int ct = 0; ct < NCT; ++ct)
      wfr[ct] = *(const bs8*)(wt + (size_t)(cs + ct * 16 + lm) * KW + kb * 32 + lg);
    bs8 afr[RT];
    #pragma unroll
    for (int rt = 0; rt < RT; ++rt)
      afr[rt] = *(const bs8*)(A + (rt * 16 + lm) * BIGLD + kb * 32 + lg);
    #pragma unroll
    for (int rt = 0; rt < RT; ++rt)
      #pragma unroll
      for (int ct = 0; ct < NCT; ++ct)
        acc[rt][ct] = __builtin_amdgcn_mfma_f32_16x16x32_bf16(wfr[ct], afr[rt], acc[rt][ct], 0, 0, 0);
  }
}

template<int RT, int NCT>
__device__ __forceinline__ void zero_acc(f4 acc[RT][NCT]) {
  #pragma unroll
  for (int rt = 0; rt < RT; ++rt)
    #pragma unroll
    for (int ct = 0; ct < NCT; ++ct) {
      acc[rt][ct][0] = 0.f; acc[rt][ct][1] = 0.f; acc[rt][ct][2] = 0.f; acc[rt][ct][3] = 0.f;
    }
}

template<int RT, int NCT, int ACTF>
__device__ __forceinline__ void storeB(unsigned short* dst,
    f4 acc[RT][NCT], const float* __restrict__ bias, int cs, int l)
{
  const int lm = l & 15;
  const int lr = (l >> 4) << 2;
  #pragma unroll
  for (int ct = 0; ct < NCT; ++ct) {
    f4 bv = *(const f4*)(bias + cs + ct * 16 + lr);
    #pragma unroll
    for (int rt = 0; rt < RT; ++rt) {
      float v[4];
      #pragma unroll
      for (int r = 0; r < 4; ++r) {
        v[r] = acc[rt][ct][r] + bv[r];
        if (ACTF == 1) v[r] = gelu_f(v[r]);
      }
      *(bs4*)(dst + (rt * 16 + lm) * BIGLD + cs + ct * 16 + lr) = pack4(v[0], v[1], v[2], v[3]);
    }
  }
}

// ---------- pre-kernels ----------
__global__ void node_ln_bf16(const float* __restrict__ x, const float* __restrict__ g,
                             const float* __restrict__ b, unsigned short* __restrict__ y)
{
  int row = blockIdx.x * 4 + (threadIdx.x >> 6);
  int lane = threadIdx.x & 63;
  float4 v = ((const float4*)(x + (size_t)row * HH))[lane];
  float s = v.x + v.y + v.z + v.w;
  float ss = v.x * v.x + v.y * v.y + v.z * v.z + v.w * v.w;
  #pragma unroll
  for (int m = 1; m < 64; m <<= 1) { s += __shfl_xor(s, m); ss += __shfl_xor(ss, m); }
  float mean = s * (1.f / HH);
  float var = ss * (1.f / HH) - mean * mean;
  float rstd = rsqrtf(var + 1e-5f);
  float4 gg = ((const float4*)g)[lane];
  float4 bb = ((const float4*)b)[lane];
  *(bs4*)(y + (size_t)row * HH + lane * 4) =
      pack4((v.x - mean) * rstd * gg.x + bb.x, (v.y - mean) * rstd * gg.y + bb.y,
            (v.z - mean) * rstd * gg.z + bb.z, (v.w - mean) * rstd * gg.w + bb.w);
}

__global__ void wt_transpose(const float* __restrict__ src, unsigned short* __restrict__ dst,
                             int K, int C)
{
  __shared__ float tile[32][33];
  int tx = threadIdx.x & 31, ty = threadIdx.x >> 5;
  int bk = blockIdx.x, bc = blockIdx.y;
  #pragma unroll
  for (int i = 0; i < 4; ++i)
    tile[ty + i * 8][tx] = src[(size_t)(bk * 32 + ty + i * 8) * C + bc * 32 + tx];
  __syncthreads();
  #pragma unroll
  for (int i = 0; i < 4; ++i)
    dst[(size_t)(bc * 32 + ty + i * 8) * K + bk * 32 + tx] = f2b(tile[tx][ty + i * 8]);
}

// ---------- mega kernel: 4 nodes / block, 512 threads ----------
__launch_bounds__(THREADS, 2)
__global__ void mega_kernel(P p)
{
  extern __shared__ unsigned short smem[];   // [128][BIGLD]

  const int tid = threadIdx.x;
  const int l = tid & 63;
  const int w = tid >> 6;           // wave 0..7
  const int lm = l & 15;
  const int lg = (l >> 4) << 3;
  const int lr = (l >> 4) << 2;
  const int n0 = blockIdx.x * NODES;
  const size_t ebase = (size_t)blockIdx.x * 128;   // global edge row base
  const int4 cnt4 = *(const int4*)(p.nbrc + n0);
  const int cnts[4] = { cnt4.x, cnt4.y, cnt4.z, cnt4.w };

  // node scratch accessors (cols 256:512, by 256-elem row chunks)
  #define FSA(i)  (*(float*)(smem + ((i) >> 7) * BIGLD + 256 + (((i) & 127) << 1)))
  #define FSNF(i) (*(float*)(smem + (8 + ((i) >> 7)) * BIGLD + 256 + (((i) & 127) << 1)))
  #define FLNP(j) (*(float*)(smem + 16 * BIGLD + 256 + ((j) << 1)))

  // ============ S0: stage ear bf16 -> cols 0:128 ============
  {
    int row = tid >> 2, q = tid & 3;
    const float* src = p.ear + (ebase + row) * DE + q * 32;
    unsigned short* d = smem + row * BIGLD + q * 32;
    #pragma unroll
    for (int j = 0; j < 8; ++j) {
      float4 v = ((const float4*)src)[j];
      *(bs4*)(d + j * 4) = pack4(v.x, v.y, v.z, v.w);
    }
  }
  __syncthreads();
  // ============ EA: eattr = gelu(ear@Wea) -> cols 0:256 (acc-then-store) ============
  {
    f4 acc[8][2]; zero_acc<8,2>(acc);
    gemmB<8,2,4,128>(acc, p.wtEA, smem, w * 32, l);
    __syncthreads();
    storeB<8,2,1>(smem, acc, p.b_ea, w * 32, l);
  }
  __syncthreads();
  // ============ S1: gather nh -> cols 264:520 ============
  {
    int row = tid >> 2, q = tid & 3;
    int idx = p.nbrl[(n0 + (row >> 5)) * KK + (row & 31)];
    const unsigned short* src = p.nhb + (size_t)idx * HH + q * 64;
    unsigned short* d = smem + row * BIGLD + 264 + q * 64;
    #pragma unroll
    for (int j = 0; j < 8; ++j) *(bs8*)(d + j * 8) = *(const bs8*)(src + j * 8);
  }
  __syncthreads();
  // ============ NH: nhid = gelu(nhg@Wnh) -> cols 256:512 ============
  {
    f4 acc[8][2]; zero_acc<8,2>(acc);
    gemmB<8,2,8,256>(acc, p.wtNH, smem + 264, w * 32, l);
    __syncthreads();
    storeB<8,2,1>(smem + 256, acc, p.b_nh, w * 32, l);
  }
  __syncthreads();
  // ============ GC: gate/cand over m = cols 0:512 (K=512) -> packed regs ============
  bs4 gp[8][2], cp[8][2];
  {
    f4 ga[8][2]; zero_acc<8,2>(ga);
    f4 ca[8][2]; zero_acc<8,2>(ca);
    gemmB<8,2,16,512>(ga, p.wtG, smem, w * 32, l);
    gemmB<8,2,16,512>(ca, p.wtC, smem, w * 32, l);
    #pragma unroll
    for (int ct = 0; ct < 2; ++ct) {
      f4 bg = *(const f4*)(p.b_gate + w * 32 + ct * 16 + lr);
      f4 bc = *(const f4*)(p.b_cand + w * 32 + ct * 16 + lr);
      #pragma unroll
      for (int rt = 0; rt < 8; ++rt) {
        gp[rt][ct] = pack4(sigmoid_f(ga[rt][ct][0] + bg[0]), sigmoid_f(ga[rt][ct][1] + bg[1]),
                           sigmoid_f(ga[rt][ct][2] + bg[2]), sigmoid_f(ga[rt][ct][3] + bg[3]));
        cp[rt][ct] = pack4(fast_tanh(ca[rt][ct][0] + bc[0]), fast_tanh(ca[rt][ct][1] + bc[1]),
                           fast_tanh(ca[rt][ct][2] + bc[2]), fast_tanh(ca[rt][ct][3] + bc[3]));
      }
    }
  }
  __syncthreads();
  // ============ S2: LN1e(ef) -> cols 0:256 ============
  {
    int row = tid >> 2, q = tid & 3;
    const float* src = p.ef + (ebase + row) * HH + q * 64;
    float s = 0.f, ss = 0.f;
    #pragma unroll
    for (int j = 0; j < 16; ++j) {
      float4 v = ((const float4*)src)[j];
      s += v.x + v.y + v.z + v.w;
      ss += v.x * v.x + v.y * v.y + v.z * v.z + v.w * v.w;
    }
    s += __shfl_xor(s, 1); ss += __shfl_xor(ss, 1);
    s += __shfl_xor(s, 2); ss += __shfl_xor(ss, 2);
    float mean = s * (1.f / HH);
    float var = ss * (1.f / HH) - mean * mean;
    float rstd = rsqrtf(var + 1e-5f);
    unsigned short* d = smem + row * BIGLD + q * 64;
    #pragma unroll
    for (int j = 0; j < 16; ++j) {
      float4 v = ((const float4*)src)[j];
      int c = q * 64 + j * 4;
      float4 g = *(const float4*)(p.ln1e_g + c);
      float4 b = *(const float4*)(p.ln1e_b + c);
      *(bs4*)(d + j * 4) = pack4((v.x - mean) * rstd * g.x + b.x,
                                 (v.y - mean) * rstd * g.y + b.y,
                                 (v.z - mean) * rstd * g.z + b.z,
                                 (v.w - mean) * rstd * g.w + b.w);
    }
  }
  __syncthreads();
  // ============ EH + msg combine -> cols 0:256 ============
  {
    f4 ea[8][2]; zero_acc<8,2>(ea);
    gemmB<8,2,8,256>(ea, p.wtEH, smem, w * 32, l);
    __syncthreads();
    #pragma unroll
    for (int ct = 0; ct < 2; ++ct) {
      f4 be = *(const f4*)(p.b_eh + w * 32 + ct * 16 + lr);
      #pragma unroll
      for (int rt = 0; rt < 8; ++rt) {
        float o[4];
        #pragma unroll
        for (int r = 0; r < 4; ++r) {
          float g = b2f((unsigned short)gp[rt][ct][r]);
          float c = b2f((unsigned short)cp[rt][ct][r]);
          float eh = gelu_f(ea[rt][ct][r] + be[r]);
          o[r] = g * c + (1.f - g) * eh;
        }
        *(bs4*)(smem + (rt * 16 + lm) * BIGLD + w * 32 + ct * 16 + lr) = pack4(o[0], o[1], o[2], o[3]);
      }
    }
  }
  __syncthreads();
  // ============ QKV: msg@Win -> packed regs (wave w = head w, cols w*32..) ============
  bs4 qp[8][2], kp[8][2], vp[8][2];
  {
    f4 acc[8][2];
    zero_acc<8,2>(acc);
    gemmB<8,2,8,256>(acc, p.wtIN, smem, w * 32, l);
    #pragma unroll
    for (int ct = 0; ct < 2; ++ct) {
      f4 bv = *(const f4*)(p.b_in + w * 32 + ct * 16 + lr);
      #pragma unroll
      for (int rt = 0; rt < 8; ++rt)
        qp[rt][ct] = pack4(acc[rt][ct][0] + bv[0], acc[rt][ct][1] + bv[1],
                           acc[rt][ct][2] + bv[2], acc[rt][ct][3] + bv[3]);
    }
    zero_acc<8,2>(acc);
    gemmB<8,2,8,256>(acc, p.wtIN + 256 * 256, smem, w * 32, l);
    #pragma unroll
    for (int ct = 0; ct < 2; ++ct) {
      f4 bv = *(const f4*)(p.b_in + 256 + w * 32 + ct * 16 + lr);
      #pragma unroll
      for (int rt = 0; rt < 8; ++rt)
        kp[rt][ct] = pack4(acc[rt][ct][0] + bv[0], acc[rt][ct][1] + bv[1],
                           acc[rt][ct][2] + bv[2], acc[rt][ct][3] + bv[3]);
    }
    zero_acc<8,2>(acc);
    gemmB<8,2,8,256>(acc, p.wtIN + 512 * 256, smem, w * 32, l);
    #pragma unroll
    for (int ct = 0; ct < 2; ++ct) {
      f4 bv = *(const f4*)(p.b_in + 512 + w * 32 + ct * 16 + lr);
      #pragma unroll
      for (int rt = 0; rt < 8; ++rt)
        vp[rt][ct] = pack4(acc[rt][ct][0] + bv[0], acc[rt][ct][1] + bv[1],
                           acc[rt][ct][2] + bv[2], acc[rt][ct][3] + bv[3]);
    }
  }
  __syncthreads();   // scratch region (cols 256:512) now free
  // ============ ATTENTION: wave w = head w, per node; wave-private scratch ============
  bs4 cxp[NODES][2][2];
  {
    const float asc = p.ascal[w];
    f4 z; z[0] = 0.f; z[1] = 0.f; z[2] = 0.f; z[3] = 0.f;
    // scratch: area a(0/1), row r(0..31), col c(0..31) -> elem
    #define WSADDR(a, r, c) ((w * 8 + (a) * 4 + ((r) >> 3)) * BIGLD + 256 + (((r) & 7) << 5) + (c))
    #pragma unroll
    for (int ni = 0; ni < NODES; ++ni) {
      // write q (area0), k (area1)
      #pragma unroll
      for (int j = 0; j < 2; ++j)
        #pragma unroll
        for (int ct = 0; ct < 2; ++ct) {
          *(bs4*)(smem + WSADDR(0, j * 16 + lm, ct * 16 + lr)) = qp[2 * ni + j][ct];
          *(bs4*)(smem + WSADDR(1, j * 16 + lm, ct * 16 + lr)) = kp[2 * ni + j][ct];
        }
      LGK_FENCE();
      bs8 qf[2], kf[2];
      #pragma unroll
      for (int t = 0; t < 2; ++t) {
        qf[t] = *(const bs8*)(smem + WSADDR(0, t * 16 + lm, lg));
        kf[t] = *(const bs8*)(smem + WSADDR(1, t * 16 + lm, lg));
      }
      f4 sc[2][2];
      #pragma unroll
      for (int kt = 0; kt < 2; ++kt)
        #pragma unroll
        for (int qt = 0; qt < 2; ++qt)
          sc[kt][qt] = __builtin_amdgcn_mfma_f32_16x16x32_bf16(kf[kt], qf[qt], z, 0, 0, 0);
      // softmax (lane holds q = qt*16+lm; k spread over lanes/regs)
      float inv[2];
      #pragma unroll
      for (int qt = 0; qt < 2; ++qt) {
        const int q = qt * 16 + lm;
        float sv[2][4];
        #pragma unroll
        for (int kt = 0; kt < 2; ++kt) {
          f4 av = *(const f4*)(p.ang + ((((size_t)(n0 + ni)) * 8 + w) * 32 + q) * 32 + kt * 16 + lr);
          #pragma unroll
          for (int r = 0; r < 4; ++r) {
            int kidx = kt * 16 + lr + r;
            sv[kt][r] = sc[kt][qt][r] * 0.17677669529663687f + av[r] * asc
                      + (kidx < cnts[ni] ? 0.f : -1e9f);
          }
        }
        float m = sv[0][0];
        #pragma unroll
        for (int r = 1; r < 4; ++r) m = fmaxf(m, sv[0][r]);
        #pragma unroll
        for (int r = 0; r < 4; ++r) m = fmaxf(m, sv[1][r]);
        m = fmaxf(m, __shfl_xor(m, 16));
        m = fmaxf(m, __shfl_xor(m, 32));
        float e[2][4], sum = 0.f;
        #pragma unroll
        for (int kt = 0; kt < 2; ++kt)
          #pragma unroll
          for (int r = 0; r < 4; ++r) { e[kt][r] = __expf(sv[kt][r] - m); sum += e[kt][r]; }
        sum += __shfl_xor(sum, 16);
        sum += __shfl_xor(sum, 32);
        inv[qt] = 1.f / sum;
        // Pt overwrites q-area (wave-ordered DS ops)
        *(bs4*)(smem + WSADDR(0, q, lr))      = pack4(e[0][0], e[0][1], e[0][2], e[0][3]);
        *(bs4*)(smem + WSADDR(0, q, 16 + lr)) = pack4(e[1][0], e[1][1], e[1][2], e[1][3]);
      }
      // Vt overwrites k-area: Vt[d][k]
      #pragma unroll
      for (int j = 0; j < 2; ++j)
        #pragma unroll
        for (int ct = 0; ct < 2; ++ct)
          #pragma unroll
          for (int r = 0; r < 4; ++r)
            smem[WSADDR(1, ct * 16 + lr + r, j * 16 + lm)] = (unsigned short)vp[2 * ni + j][ct][r];
      LGK_FENCE();
      bs8 pf[2], vf[2];
      #pragma unroll
      for (int t = 0; t < 2; ++t) {
        pf[t] = *(const bs8*)(smem + WSADDR(0, t * 16 + lm, lg));
        vf[t] = *(const bs8*)(smem + WSADDR(1, t * 16 + lm, lg));
      }
      #pragma unroll
      for (int qt = 0; qt < 2; ++qt)
        #pragma unroll
        for (int dt = 0; dt < 2; ++dt) {
          f4 cx = __builtin_amdgcn_mfma_f32_16x16x32_bf16(vf[dt], pf[qt], z, 0, 0, 0);
          cxp[ni][qt][dt] = pack4(cx[0] * inv[qt], cx[1] * inv[qt], cx[2] * inv[qt], cx[3] * inv[qt]);
        }
    }
    #undef WSADDR
  }
  __syncthreads();
  // ctx -> cols 256:512
  {
    #pragma unroll
    for (int ni = 0; ni < NODES; ++ni)
      #pragma unroll
      for (int qt = 0; qt < 2; ++qt)
        #pragma unroll
        for (int dt = 0; dt < 2; ++dt)
          *(bs4*)(smem + (ni * 32 + qt * 16 + lm) * BIGLD + 256 + w * 32 + dt * 16 + lr) = cxp[ni][qt][dt];
  }
  __syncthreads();
  // ============ OUT: eo = ctx@Wout + b -> cols 0:256 ============
  {
    f4 acc[8][2]; zero_acc<8,2>(acc);
    gemmB<8,2,8,256>(acc, p.wtOUT, smem + 256, w * 32, l);
    __syncthreads();
    storeB<8,2,0>(smem, acc, p.b_out, w * 32, l);
  }
  __syncthreads();
  // ============ alpha fill ============
  {
    #pragma unroll
    for (int it = 0; it < 2; ++it) {
      int idx = tid + it * 512;              // 0..1023
      int ni = idx >> 8, rem = idx & 255;
      int k = rem >> 3, h = rem & 7;
      float aa = 0.f;
      #pragma unroll
      for (int j = 0; j < 8; ++j) {
        bs4 ev = *(const bs4*)(smem + (ni * 32 + k) * BIGLD + h * 32 + j * 4);
        float4 av = *(const float4*)(p.aw + h * 32 + j * 4);
        aa += b2f((unsigned short)ev[0]) * av.x + b2f((unsigned short)ev[1]) * av.y
            + b2f((unsigned short)ev[2]) * av.z + b2f((unsigned short)ev[3]) * av.w;
      }
      aa = aa > 0.f ? aa : 0.2f * aa;
      if (k >= cnts[ni]) aa = -1e9f;
      FSA(idx) = aa;
    }
  }
  __syncthreads();
  // ============ alpha softmax over k: 16-lane groups (round-4 form), all 512 threads ============
  {
    int ni = tid >> 7, h = (tid >> 4) & 7, l16 = tid & 15;
    float v0 = FSA(ni * 256 + l16 * 8 + h);
    float v1 = FSA(ni * 256 + (l16 + 16) * 8 + h);
    float m = fmaxf(v0, v1);
    m = fmaxf(m, __shfl_xor(m, 1));
    m = fmaxf(m, __shfl_xor(m, 2));
    m = fmaxf(m, __shfl_xor(m, 4));
    m = fmaxf(m, __shfl_xor(m, 8));
    float e0 = __expf(v0 - m), e1 = __expf(v1 - m);
    float s = e0 + e1;
    s += __shfl_xor(s, 1);
    s += __shfl_xor(s, 2);
    s += __shfl_xor(s, 4);
    s += __shfl_xor(s, 8);
    float inv = 1.f / s;
    FSA(ni * 256 + l16 * 8 + h) = e0 * inv;
    FSA(ni * 256 + (l16 + 16) * 8 + h) = e1 * inv;
  }
  __syncthreads();
  // ============ aggregate (pass 1): nodef + per-wave LN partials ============
  float ndf[2];
  {
    #pragma unroll
    for (int it = 0; it < 2; ++it) {
      int idx = it * 512 + tid;
      int ni = idx >> 8, c = idx & 255, h = c >> 5;
      float no = 0.f;
      #pragma unroll
      for (int k = 0; k < 32; ++k)
        no = fmaf(FSA(ni * 256 + k * 8 + h), b2f(smem[(ni * 32 + k) * BIGLD + c]), no);
      float nodef = no + p.nf[(size_t)(n0 + ni) * HH + c];
      ndf[it] = nodef;
      FSNF(idx) = nodef;
      float s = nodef, ss = nodef * nodef;
      #pragma unroll
      for (int m = 1; m < 64; m <<= 1) { s += __shfl_xor(s, m); ss += __shfl_xor(ss, m); }
      if (l == 0) { FLNP(it * 8 + w) = s; FLNP(16 + it * 8 + w) = ss; }
    }
  }
  __syncthreads();
  // ============ LN2n (pass 2) -> NSTG rows 17..20 ; zero FFN1 garbage rows 21..32 ============
  {
    #pragma unroll
    for (int it = 0; it < 2; ++it) {
      int idx = it * 512 + tid;
      int ni = idx >> 8, c = idx & 255;
      int base = it * 8 + (ni & 1) * 4;
      float S  = FLNP(base) + FLNP(base + 1) + FLNP(base + 2) + FLNP(base + 3);
      float SS = FLNP(16 + base) + FLNP(16 + base + 1) + FLNP(16 + base + 2) + FLNP(16 + base + 3);
      float mean = S * (1.f / HH), var = SS * (1.f / HH) - mean * mean;
      float rstd = rsqrtf(var + 1e-5f);
      smem[(17 + ni) * BIGLD + 256 + c] = f2b((ndf[it] - mean) * rstd * p.ln2n_g[c] + p.ln2n_b[c]);
    }
    #pragma unroll
    for (int z = 0; z < 3; ++z) {
      int zi = z * 512 + tid;             // 0..1535 -> rows 21..32, 128 uints each
      int zr = 21 + (zi >> 7), zc = (zi & 127) << 1;
      *(unsigned int*)(smem + zr * BIGLD + 256 + zc) = 0u;
    }
  }
  __syncthreads();
  // ============ node FFN1 (nodes packed in lane dim; rows 21..32 now zero) ============
  {
    f4 acc[4];
    #pragma unroll
    for (int ct = 0; ct < 4; ++ct) { acc[ct][0]=0.f; acc[ct][1]=0.f; acc[ct][2]=0.f; acc[ct][3]=0.f; }
    #pragma unroll
    for (int kb = 0; kb < 8; ++kb) {
      bs8 afr = *(const bs8*)(smem + (17 + lm) * BIGLD + 256 + kb * 32 + lg);
      #pragma unroll
      for (int ct = 0; ct < 4; ++ct) {
        bs8 wfr = *(const bs8*)(p.wtN1 + (size_t)(w * 64 + ct * 16 + lm) * 256 + kb * 32 + lg);
        acc[ct] = __builtin_amdgcn_mfma_f32_16x16x32_bf16(wfr, afr, acc[ct], 0, 0, 0);
      }
    }
    __syncthreads();
    #pragma unroll
    for (int ct = 0; ct < 4; ++ct) {
      int col = w * 64 + ct * 16 + lr;
      f4 bv = *(const f4*)(p.bn1 + col);
      *(bs4*)(smem + (33 + 2 * lm + (col >= 256 ? 1 : 0)) * BIGLD + 256 + (col & 255)) =
          pack4(gelu_f(acc[ct][0] + bv[0]), gelu_f(acc[ct][1] + bv[1]),
                gelu_f(acc[ct][2] + bv[2]), gelu_f(acc[ct][3] + bv[3]));
    }
  }
  __syncthreads();
  // ============ node FFN2 + residual -> on ; also pack edge_f regs ============
  bs4 efp[8][2];
  {
    f4 acc[2];
    #pragma unroll
    for (int ct = 0; ct < 2; ++ct) { acc[ct][0]=0.f; acc[ct][1]=0.f; acc[ct][2]=0.f; acc[ct][3]=0.f; }
    #pragma unroll
    for (int kb = 0; kb < 16; ++kb) {
      bs8 afr = *(const bs8*)(smem + (33 + 2 * lm + (kb >> 3)) * BIGLD + 256 + (kb & 7) * 32 + lg);
      #pragma unroll
      for (int ct = 0; ct < 2; ++ct) {
        bs8 wfr = *(const bs8*)(p.wtN2 + (size_t)(w * 32 + ct * 16 + lm) * 512 + kb * 32 + lg);
        acc[ct] = __builtin_amdgcn_mfma_f32_16x16x32_bf16(wfr, afr, acc[ct], 0, 0, 0);
      }
    }
    if (lm < 4) {
      #pragma unroll
      for (int ct = 0; ct < 2; ++ct) {
        int col = w * 32 + ct * 16 + lr;
        f4 bv = *(const f4*)(p.bn2 + col);
        float4 o;
        o.x = acc[ct][0] + bv[0] + FSNF(lm * 256 + col);
        o.y = acc[ct][1] + bv[1] + FSNF(lm * 256 + col + 1);
        o.z = acc[ct][2] + bv[2] + FSNF(lm * 256 + col + 2);
        o.w = acc[ct][3] + bv[3] + FSNF(lm * 256 + col + 3);
        *(float4*)(p.on + (size_t)(n0 + lm) * HH + col) = o;
      }
    }
    // edge_f = eo + ef packed into regs (tile layout matching E2 epilogue)
    #pragma unroll
    for (int rt = 0; rt < 8; ++rt)
      #pragma unroll
      for (int ct = 0; ct < 2; ++ct) {
        int row = rt * 16 + lm, col = w * 32 + ct * 16 + lr;
        bs4 ov = *(const bs4*)(smem + row * BIGLD + col);
        float4 e = *(const float4*)(p.ef + (ebase + row) * HH + col);
        efp[rt][ct] = pack4(e.x + b2f((unsigned short)ov[0]), e.y + b2f((unsigned short)ov[1]),
                            e.z + b2f((unsigned short)ov[2]), e.w + b2f((unsigned short)ov[3]));
      }
  }
  __syncthreads();
  // ============ LN2e(eo + ef) -> cols 0:256 (overwrite eo) ============
  {
    int row = tid >> 2, q = tid & 3;
    const float* efs = p.ef + (ebase + row) * HH + q * 64;
    const unsigned short* eor = smem + row * BIGLD + q * 64;
    float xv[64];
    float s = 0.f, ss = 0.f;
    #pragma unroll
    for (int j = 0; j < 16; ++j) {
      float4 e = ((const float4*)efs)[j];
      bs4 ov = *(const bs4*)(eor + j * 4);
      float x0 = e.x + b2f((unsigned short)ov[0]);
      float x1 = e.y + b2f((unsigned short)ov[1]);
      float x2 = e.z + b2f((unsigned short)ov[2]);
      float x3 = e.w + b2f((unsigned short)ov[3]);
      xv[j * 4] = x0; xv[j * 4 + 1] = x1; xv[j * 4 + 2] = x2; xv[j * 4 + 3] = x3;
      s += x0 + x1 + x2 + x3;
      ss += x0 * x0 + x1 * x1 + x2 * x2 + x3 * x3;
    }
    s += __shfl_xor(s, 1); ss += __shfl_xor(ss, 1);
    s += __shfl_xor(s, 2); ss += __shfl_xor(ss, 2);
    float mean = s * (1.f / HH);
    float var = ss * (1.f / HH) - mean * mean;
    float rstd = rsqrtf(var + 1e-5f);
    unsigned short* d = smem + row * BIGLD + q * 64;
    #pragma unroll
    for (int j = 0; j < 16; ++j) {
      int c = q * 64 + j * 4;
      float4 g = *(const float4*)(p.ln2e_g + c);
      float4 b = *(const float4*)(p.ln2e_b + c);
      *(bs4*)(d + j * 4) = pack4((xv[j * 4] - mean) * rstd * g.x + b.x,
                                 (xv[j * 4 + 1] - mean) * rstd * g.y + b.y,
                                 (xv[j * 4 + 2] - mean) * rstd * g.z + b.z,
                                 (xv[j * 4 + 3] - mean) * rstd * g.w + b.w);
    }
  }
  __syncthreads();
  // ============ edge FFN: two K-halves, E2 register accumulator ============
  f4 oacc[8][2]; zero_acc<8,2>(oacc);
  {
    f4 h[8][2]; zero_acc<8,2>(h);
    gemmB<8,2,8,256>(h, p.wtE1, smem, w * 32, l);
    __syncthreads();
    storeB<8,2,1>(smem + 256, h, p.be1, w * 32, l);
  }
  __syncthreads();
  {
    gemmB<8,2,8,512>(oacc, p.wtE2, smem + 256, w * 32, l);
    f4 h[8][2]; zero_acc<8,2>(h);
    gemmB<8,2,8,256>(h, p.wtE1 + (size_t)256 * 256, smem, w * 32, l);
    __syncthreads();
    storeB<8,2,1>(smem + 256, h, p.be1 + 256, w * 32, l);
  }
  __syncthreads();
  {
    gemmB<8,2,8,512>(oacc, p.wtE2 + 256, smem + 256, w * 32, l);
    #pragma unroll
    for (int ct = 0; ct < 2; ++ct) {
      f4 bv = *(const f4*)(p.be2 + w * 32 + ct * 16 + lr);
      #pragma unroll
      for (int rt = 0; rt < 8; ++rt) {
        int row = rt * 16 + lm;
        float4 o;
        o.x = oacc[rt][ct][0] + bv[0] + b2f((unsigned short)efp[rt][ct][0]);
        o.y = oacc[rt][ct][1] + bv[1] + b2f((unsigned short)efp[rt][ct][1]);
        o.z = oacc[rt][ct][2] + bv[2] + b2f((unsigned short)efp[rt][ct][2]);
        o.w = oacc[rt][ct][3] + bv[3] + b2f((unsigned short)efp[rt][ct][3]);
        *(float4*)(p.oe + (ebase + row) * HH + w * 32 + ct * 16 + lr) = o;
      }
    }
  }
  #undef FSA
  #undef FSNF
  #undef FLNP
}

extern "C" void kernel_launch(void* const* d_in, const int* in_sizes, int n_in,
                              void* d_out, int out_size, void* d_ws, size_t ws_size,
                              hipStream_t stream)
{
  P p;
  p.nf     = (const float*)d_in[0];
  p.ef     = (const float*)d_in[1];
  p.ear    = (const float*)d_in[2];
  p.ang    = (const float*)d_in[3];
  const float* ln1n_g = (const float*)d_in[4];
  const float* ln1n_b = (const float*)d_in[5];
  p.ln1e_g = (const float*)d_in[6];  p.ln1e_b = (const float*)d_in[7];
  const float* W_ea   = (const float*)d_in[8];  p.b_ea   = (const float*)d_in[9];
  const float* W_nh   = (const float*)d_in[10]; p.b_nh   = (const float*)d_in[11];
  const float* W_eh   = (const float*)d_in[12]; p.b_eh   = (const float*)d_in[13];
  const float* W_gate = (const float*)d_in[14]; p.b_gate = (const float*)d_in[15];
  const float* W_cand = (const float*)d_in[16]; p.b_cand = (const float*)d_in[17];
  p.ascal  = (const float*)d_in[18];
  const float* W_in   = (const float*)d_in[19]; p.b_in   = (const float*)d_in[20];
  const float* W_out  = (const float*)d_in[21]; p.b_out  = (const float*)d_in[22];
  p.aw     = (const float*)d_in[23];
  p.ln2n_g = (const float*)d_in[24]; p.ln2n_b = (const float*)d_in[25];
  p.ln2e_g = (const float*)d_in[26]; p.ln2e_b = (const float*)d_in[27];
  const float* Wn1 = (const float*)d_in[28]; p.bn1 = (const float*)d_in[29];
  const float* Wn2 = (const float*)d_in[30]; p.bn2 = (const float*)d_in[31];
  const float* We1 = (const float*)d_in[32]; p.be1 = (const float*)d_in[33];
  const float* We2 = (const float*)d_in[34]; p.be2 = (const float*)d_in[35];
  p.nbrl   = (const int*)d_in[36];
  p.nbrc   = (const int*)d_in[37];
  p.on     = (float*)d_out;
  p.oe     = (float*)d_out + (size_t)NN * HH;

  size_t off = 0;
  auto alloc = [&](size_t elems) {
    unsigned short* q = (unsigned short*)((char*)d_ws + off);
    off += elems * 2;
    return q;
  };
  unsigned short* nhb = alloc((size_t)NN * HH);
  unsigned short* wtEA  = alloc(256 * 128);
  unsigned short* wtNH  = alloc(256 * 256);
  unsigned short* wtEH  = alloc(256 * 256);
  unsigned short* wtG   = alloc(256 * 512);
  unsigned short* wtC   = alloc(256 * 512);
  unsigned short* wtIN  = alloc(768 * 256);
  unsigned short* wtOUT = alloc(256 * 256);
  unsigned short* wtN1  = alloc(512 * 256);
  unsigned short* wtN2  = alloc(256 * 512);
  unsigned short* wtE1  = alloc(512 * 256);
  unsigned short* wtE2  = alloc(256 * 512);
  p.nhb = nhb;
  p.wtEA = wtEA; p.wtNH = wtNH; p.wtEH = wtEH; p.wtG = wtG; p.wtC = wtC;
  p.wtIN = wtIN; p.wtOUT = wtOUT; p.wtN1 = wtN1; p.wtN2 = wtN2; p.wtE1 = wtE1; p.wtE2 = wtE2;

  node_ln_bf16<<<NN / 4, 256, 0, stream>>>((const float*)d_in[0], ln1n_g, ln1n_b, nhb);

  auto tr = [&](const float* src, unsigned short* dst, int K, int C) {
    wt_transpose<<<dim3(K / 32, C / 32), 256, 0, stream>>>(src, dst, K, C);
  };
  tr(W_ea, wtEA, 128, 256);
  tr(W_nh, wtNH, 256, 256);
  tr(W_eh, wtEH, 256, 256);
  tr(W_gate, wtG, 512, 256);
  tr(W_cand, wtC, 512, 256);
  tr(W_in, wtIN, 256, 768);
  tr(W_out, wtOUT, 256, 256);
  tr(Wn1, wtN1, 256, 512);
  tr(Wn2, wtN2, 512, 256);
  tr(We1, wtE1, 256, 512);
  tr(We2, wtE2, 512, 256);

  (void)hipFuncSetAttribute((const void*)mega_kernel,
                            hipFuncAttributeMaxDynamicSharedMemorySize, LDS_BYTES);
  mega_kernel<<<NN / NODES, THREADS, LDS_BYTES, stream>>>(p);
}